// Round 14
// baseline (418.420 us; speedup 1.0000x reference)
//
#include <hip/hip_runtime.h>

#define HH 512
#define WW 512
#define BB 8
#define IMG (HH*WW)
#define NTOT (BB*IMG)

typedef float f32x4 __attribute__((ext_vector_type(4)));
typedef _Float16 half8 __attribute__((ext_vector_type(8)));

__device__ inline uint f2h2(float a, float b) {
  uint d; asm("v_cvt_pkrtz_f16_f32 %0, %1, %2" : "=v"(d) : "v"(a), "v"(b)); return d;
}
__device__ inline uint pkfma(uint a, uint b, uint c) {
  uint d; asm("v_pk_fma_f16 %0, %1, %2, %3" : "=v"(d) : "v"(a), "v"(b), "v"(c)); return d;
}
__device__ inline uint pkmax0(uint a) {
  uint d, z = 0u; asm("v_pk_max_f16 %0, %1, %2" : "=v"(d) : "v"(a), "v"(z)); return d;
}

__device__ inline void atomic_block_sum(float part, float* red, float* dst) {
  for (int off = 32; off > 0; off >>= 1) part += __shfl_down(part, off, 64);
  int lane = threadIdx.x & 63, w = threadIdx.x >> 6;
  if (lane == 0) red[w] = part;
  __syncthreads();
  if (threadIdx.x == 0) atomicAdd(dst, red[0] + red[1] + red[2] + red[3]);
}

__device__ inline void reduce3_atomic(float a, float b, float c, float* red,
                                      float* da, float* db, float* dc) {
  for (int off = 32; off > 0; off >>= 1) {
    a += __shfl_down(a, off, 64);
    b += __shfl_down(b, off, 64);
    c += __shfl_down(c, off, 64);
  }
  int lane = threadIdx.x & 63, w = threadIdx.x >> 6;
  if (lane == 0) { red[w*3] = a; red[w*3+1] = b; red[w*3+2] = c; }
  __syncthreads();
  if (threadIdx.x == 0) {
    atomicAdd(da, red[0]+red[3]+red[6]+red[9]);
    if (db) atomicAdd(db, red[1]+red[4]+red[7]+red[10]);
    if (dc) atomicAdd(dc, red[2]+red[5]+red[8]+red[11]);
  }
}

// masks for boundary-corrected stencils: t = 0(row0),1(row1),2(interior),3(H-2),4(H-1)
__device__ inline bool mA5(int t, int e) {
  return (t==0) ? (e<=2) : (t==1) ? (e<=3) : (t==3) ? (e>=1) : (t==4) ? (e>=2) : true;
}
__device__ inline bool mW3(int t, int e) {
  return (t==0) ? (e<=1) : (t==4) ? (e>=1) : true;
}

// ---------------- prep: scalars, 25x81 stencil table, fp16 weight packing ----------
__global__ void k_prep(const float* __restrict__ Ka, const float* __restrict__ Kw,
                       const float* __restrict__ miu,
                       const float* __restrict__ W1, const float* __restrict__ b1,
                       const float* __restrict__ W2, const float* __restrict__ W3,
                       float* __restrict__ tab, ushort* __restrict__ w2pk,
                       uint* __restrict__ w1pk, uint* __restrict__ b1pk,
                       ushort* __restrict__ w3fr, float* __restrict__ scal) {
  __shared__ float lka[25], lkw[36], lw1[288], lw3[288];
  int tid = threadIdx.x;   // 1024 threads
  if (tid < 192) scal[tid] = 0.f;
  if (tid < 25) lka[tid] = Ka[tid];
  if (tid < 36) lkw[tid] = Kw[tid];
  if (tid < 288) { lw1[tid] = W1[tid]; lw3[tid] = W3[tid]; }
  __syncthreads();
  const float mu = miu[0];
  #pragma unroll
  for (int k = 0; k < 2; k++) {
    int idx = tid + k*1024;
    if (idx < 2025) {
      int c = idx / 81, o = idx - c*81;
      int ty = c / 5, tx = c - 5*ty;
      int uy = o / 9 - 4, ux = o % 9 - 4;
      float s = 0.f;
      for (int ey = 0; ey < 5; ey++)
        for (int ex = 0; ex < 5; ex++) {
          int dy = ey + uy, dx = ex + ux;
          if (dy >= 0 && dy < 5 && dx >= 0 && dx < 5 && mA5(ty,ey) && mA5(tx,ex))
            s += lka[ey*5+ex] * lka[dy*5+dx];
        }
      float sw = 0.f;
      for (int ch = 0; ch < 4; ch++)
        for (int ey = 0; ey < 3; ey++)
          for (int ex = 0; ex < 3; ex++) {
            int dy = ey + uy, dx = ex + ux;
            if (dy >= 0 && dy < 3 && dx >= 0 && dx < 3 && mW3(ty,ey) && mW3(tx,ex))
              sw += lkw[ch*9+ey*3+ex] * lkw[ch*9+dy*3+dx];
          }
      tab[idx] = s + mu * sw;
    }
  }
  #pragma unroll
  for (int k = 0; k < 9; k++) {
    int i = tid + k*1024;
    int j = i & 7, l = (i >> 3) & 63, f = i >> 9;
    int t5 = f >> 1, h = f & 1;
    int co = 16*h + (l & 15), ci = 8*(l >> 4) + j;
    w2pk[i] = (ushort)(f2h2(W2[(co*32 + ci)*9 + t5], 0.f) & 0xffffu);
  }
  if (tid < 144) {
    int cp = tid / 9, t = tid % 9;
    w1pk[tid] = f2h2(lw1[(2*cp)*9 + t], lw1[(2*cp+1)*9 + t]);
  }
  if (tid < 16) b1pk[tid] = f2h2(b1[2*tid], b1[2*tid+1]);
  if (tid < 512) {
    int j = tid & 7, l = tid >> 3;
    int tap = l & 15, ch = 8*(l >> 4) + j;
    w3fr[tid] = (tap < 9) ? (ushort)(f2h2(lw3[ch*9 + tap], 0.f) & 0xffffu) : (ushort)0;
  }
}

// ---------------- fused CNN: xk = cnn(x), fp16/MFMA --------------------------------
__launch_bounds__(512, 2)
__global__ void k_cnn(const float* __restrict__ x,
                      const ushort* __restrict__ w2pk, const uint* __restrict__ w1pk,
                      const uint* __restrict__ b1pk, const ushort* __restrict__ w3fr,
                      const float* __restrict__ b2, const float* __restrict__ b3,
                      float* __restrict__ xk) {
  __shared__ __align__(16) uint  h1u[7040];         // 20 x 352
  __shared__ __align__(16) uint  h2u[5472];         // 18 x 304; head doubles as xs
  uint* xs_h2 = h2u;

  const int tid = threadIdx.x;
  const int bimg = blockIdx.z;
  const int oy0 = blockIdx.y * 16, ox0 = blockIdx.x * 16;
  const float* xim = x + (size_t)bimg * IMG;

  for (int i = tid; i < 528; i += 512) {
    int ly = i / 24, lx = i % 24;
    int gy = oy0 + ly - 3, gx = ox0 + lx - 4;
    float v = 0.f;
    if ((unsigned)gy < HH && (unsigned)gx < WW) v = xim[gy*WW + gx];
    xs_h2[i] = f2h2(v, v);
  }
  __syncthreads();

  // ---- conv1 ----
  {
    const int cp = tid & 15;
    const int sg = tid >> 4;
    uint w1r[9];
    #pragma unroll
    for (int k = 0; k < 9; k++) w1r[k] = w1pk[cp*9 + k];
    const uint b1v = b1pk[cp];
    const int kg = cp >> 2, cl = cp & 3;
    #pragma unroll 1
    for (int s = sg; s < 100; s += 32) {
      int row = s / 5, st = s - 5*row;
      int px0 = st * 4;
      uint acc0 = b1v, acc1 = b1v, acc2 = b1v, acc3 = b1v;
      #pragma unroll
      for (int ky = 0; ky < 3; ky++) {
        int base = (row + ky) * 24 + px0;
        uint4 xa = *(const uint4*)&xs_h2[base];
        uint4 xb = *(const uint4*)&xs_h2[base + 4];
        uint xu[8] = {xa.x, xa.y, xa.z, xa.w, xb.x, xb.y, xb.z, xb.w};
        #pragma unroll
        for (int kx = 0; kx < 3; kx++) {
          uint w = w1r[ky*3 + kx];
          acc0 = pkfma(w, xu[1 + kx], acc0);
          acc1 = pkfma(w, xu[2 + kx], acc1);
          acc2 = pkfma(w, xu[3 + kx], acc2);
          acc3 = pkfma(w, xu[4 + kx], acc3);
        }
      }
      int Y = oy0 + row - 2;
      bool rin = (unsigned)Y < HH;
      int ob = row*352 + kg*88 + px0*4 + cl;
      #pragma unroll
      for (int i = 0; i < 4; i++) {
        int X = ox0 + px0 + i - 2;
        uint v = (rin && (unsigned)X < WW) ?
                 pkmax0(i == 0 ? acc0 : (i == 1 ? acc1 : (i == 2 ? acc2 : acc3))) : 0u;
        h1u[ob + i*4] = v;
      }
    }
  }
  __syncthreads();

  // ---- conv2 via MFMA f16 ----
  const int wv = tid >> 6, lane = tid & 63;
  const int nn = lane & 15, kg = lane >> 4;
  {
    half8 afr[9][2];
    #pragma unroll
    for (int t5 = 0; t5 < 9; t5++) {
      afr[t5][0] = ((const half8*)w2pk)[(t5*2 + 0)*64 + lane];
      afr[t5][1] = ((const half8*)w2pk)[(t5*2 + 1)*64 + lane];
    }
    float b2A[4], b2B[4];
    #pragma unroll
    for (int j = 0; j < 4; j++) { b2A[j] = b2[4*kg + j]; b2B[j] = b2[16 + 4*kg + j]; }

    #pragma unroll 1
    for (int t = wv; t < 27; t += 8) {
      int rp = t / 3, cs = t - 3*rp;
      int tx0 = (cs == 2) ? 10 : (cs << 3);
      int brow = 2*rp + (nn >> 3);
      int bcol = tx0 + (nn & 7);
      f32x4 accA = {0.f,0.f,0.f,0.f}, accB = {0.f,0.f,0.f,0.f};
      #pragma unroll
      for (int ky = 0; ky < 3; ky++)
        #pragma unroll
        for (int kx = 0; kx < 3; kx++) {
          const half8 bfr = *(const half8*)&h1u[(brow+ky)*352 + kg*88 + (bcol+kx)*4];
          accA = __builtin_amdgcn_mfma_f32_16x16x32_f16(afr[ky*3+kx][0], bfr, accA, 0, 0, 0);
          accB = __builtin_amdgcn_mfma_f32_16x16x32_f16(afr[ky*3+kx][1], bfr, accB, 0, 0, 0);
        }
      int gy = oy0 + brow - 1, gx = ox0 + bcol - 1;
      bool inb = ((unsigned)gy < HH) && ((unsigned)gx < WW);
      float v0 = inb ? fmaxf(accA[0] + b2A[0], 0.f) : 0.f;
      float v1 = inb ? fmaxf(accA[1] + b2A[1], 0.f) : 0.f;
      float v2 = inb ? fmaxf(accA[2] + b2A[2], 0.f) : 0.f;
      float v3 = inb ? fmaxf(accA[3] + b2A[3], 0.f) : 0.f;
      uint2 uA = make_uint2(f2h2(v0, v1), f2h2(v2, v3));
      v0 = inb ? fmaxf(accB[0] + b2B[0], 0.f) : 0.f;
      v1 = inb ? fmaxf(accB[1] + b2B[1], 0.f) : 0.f;
      v2 = inb ? fmaxf(accB[2] + b2B[2], 0.f) : 0.f;
      v3 = inb ? fmaxf(accB[3] + b2B[3], 0.f) : 0.f;
      uint2 uB = make_uint2(f2h2(v0, v1), f2h2(v2, v3));
      int base = brow*304 + bcol*4 + (kg & 1)*2;
      *(uint2*)&h2u[base + (kg >> 1)*76]       = uA;
      *(uint2*)&h2u[base + (2 + (kg >> 1))*76] = uB;
    }
  }
  __syncthreads();

  // ---- conv3 stage 1 via MFMA (Tlds aliased onto dead h1u) ----
  float* Tlds = (float*)h1u;
  {
    const half8 w3f = ((const half8*)w3fr)[lane];
    const int tap = nn;
    #pragma unroll 1
    for (int t = wv; t < 27; t += 8) {
      int rp = t / 3, cs = t - 3*rp;
      int tx0 = (cs == 2) ? 10 : (cs << 3);
      int ay = 2*rp + (nn >> 3);
      int ax = tx0 + (nn & 7);
      const half8 afrag = *(const half8*)&h2u[ay*304 + kg*76 + ax*4];
      f32x4 z = {0.f,0.f,0.f,0.f};
      f32x4 T4 = __builtin_amdgcn_mfma_f32_16x16x32_f16(afrag, w3f, z, 0, 0, 0);
      if (tap < 9) {
        int ty = 2*rp + (kg >> 1);
        int txb = tx0 + 4*(kg & 1);
        float* dst = &Tlds[ty*180 + tap*20 + txb];
        if (cs == 2) {
          dst[0] = T4[0]; dst[1] = T4[1]; dst[2] = T4[2]; dst[3] = T4[3];
        } else {
          *(f32x4*)dst = T4;
        }
      }
    }
  }
  __syncthreads();

  // ---- conv3 gather + residual ----
  {
    const int half = tid & 1, px = tid >> 1;
    const int oy = px >> 4, ox = px & 15;
    float s = 0.f;
    if (half == 0) {
      #pragma unroll
      for (int t = 0; t < 4; t++)
        s += Tlds[(oy + t/3)*180 + t*20 + (ox + t%3)];
    } else {
      #pragma unroll
      for (int t = 4; t < 9; t++)
        s += Tlds[(oy + t/3)*180 + t*20 + (ox + t%3)];
    }
    float other = __shfl_xor(s, 1, 64);
    if (half == 0) {
      float tot = s + other + b3[0] + xim[(size_t)(oy0+oy)*WW + ox0 + ox];
      xk[(size_t)bimg*IMG + (size_t)(oy0+oy)*WW + ox0 + ox] = tot;
    }
  }
}

// ---------------- M-apply: G-stencil + table-corrected boundary band ---------------
__device__ __forceinline__ void apply_M2(const float (*ssrc)[76], float* bandv,
    const float* Gs, const float* __restrict__ tab,
    int tid, int oy0, int ox0, float* accv) {
  const int sy = tid >> 3, sx0 = (tid & 7) * 8;
  #pragma unroll
  for (int k = 0; k < 8; k++) accv[k] = 0.f;
  #pragma unroll 1
  for (int oyy = 0; oyy < 9; oyy++) {
    float g[9];
    #pragma unroll
    for (int t = 0; t < 9; t++) g[t] = Gs[oyy*9+t];
    const float* row = &ssrc[sy+oyy][sx0];
    float4 r0 = *(const float4*)(row);
    float4 r1 = *(const float4*)(row+4);
    float4 r2 = *(const float4*)(row+8);
    float4 r3 = *(const float4*)(row+12);
    float v[16] = {r0.x,r0.y,r0.z,r0.w, r1.x,r1.y,r1.z,r1.w,
                   r2.x,r2.y,r2.z,r2.w, r3.x,r3.y,r3.z,r3.w};
    #pragma unroll
    for (int k = 0; k < 8; k++) {
      float a = accv[k];
      #pragma unroll
      for (int t = 0; t < 9; t++) a = fmaf(g[t], v[k+t], a);
      accv[k] = a;
    }
  }
  const int by = blockIdx.y, bx = blockIdx.x;
  const bool eT = (by == 0), eB = (by == (int)gridDim.y - 1);
  const bool eL = (bx == 0), eR = (bx == (int)gridDim.x - 1);
  if (eT | eB | eL | eR) {
    const int nTop = eT ? 128 : 0;
    const int nBot = eB ? 128 : 0;
    const int yl = eT ? 2 : 0, yh = eB ? 30 : 32;
    const int nL = eL ? 2*(yh-yl) : 0;
    const int nR = eR ? 2*(yh-yl) : 0;
    const int nBand = nTop + nBot + nL + nR;
    if (tid < nBand) {
      int i = tid, bsy, bsx;
      if (i < nTop) { bsy = i >> 6; bsx = i & 63; }
      else if (i < nTop + nBot) { i -= nTop; bsy = 30 + (i >> 6); bsx = i & 63; }
      else if (i < nTop + nBot + nL) { i -= nTop + nBot; bsy = yl + (i >> 1); bsx = i & 1; }
      else { i -= nTop + nBot + nL; bsy = yl + (i >> 1); bsx = 62 + (i & 1); }
      const int gy = oy0 + bsy, gx = ox0 + bsx;
      int ty = (gy == 0) ? 0 : (gy == 1) ? 1 : (gy == HH-1) ? 4 : (gy == HH-2) ? 3 : 2;
      int tx = (gx == 0) ? 0 : (gx == 1) ? 1 : (gx == WW-1) ? 4 : (gx == WW-2) ? 3 : 2;
      const float* S = tab + (ty*5 + tx)*81;
      float a = 0.f;
      #pragma unroll
      for (int oy = 0; oy < 9; oy++) {
        const float* r = &ssrc[bsy+oy][bsx];
        #pragma unroll
        for (int ox = 0; ox < 9; ox++) a = fmaf(S[oy*9+ox], r[ox], a);
      }
      bandv[tid] = a;
    }
    __syncthreads();
    #pragma unroll
    for (int k = 0; k < 8; k++) {
      const int sx = sx0 + k;
      const int gy = oy0 + sy, gx = ox0 + sx;
      if ((gy < 2) || (gy >= HH-2) || (gx < 2) || (gx >= WW-2)) {
        int idx;
        if (eT && sy < 2) idx = sy*64 + sx;
        else if (eB && sy >= 30) idx = nTop + (sy-30)*64 + sx;
        else if (eL && sx < 2) idx = nTop + nBot + (sy-yl)*2 + sx;
        else idx = nTop + nBot + nL + (sy-yl)*2 + (sx-62);
        accv[k] = bandv[idx];
      }
    }
  }
}

// ---------------- k_M01: fused {r = M(xk)-rhs, p=-r, q0=M(p), all scalars} ---------
// Computes p0 = rhs - M(xk) on the EXTENDED 40x72 region (halo 4) so q0 = M(p0)
// can be applied locally without a second kernel.
__launch_bounds__(256)
__global__ void k_M01(const float* __restrict__ xk, const float* __restrict__ sino,
                      const float* __restrict__ x,
                      float* __restrict__ outR, float* __restrict__ outP,
                      float* __restrict__ outQ,
                      const float* __restrict__ tab,
                      const float* __restrict__ Ka, const float* __restrict__ Kw,
                      const float* __restrict__ laam, const float* __restrict__ miu,
                      float* __restrict__ scal) {
  __shared__ __align__(16) float ssrcX[48][84];   // xk, halo 8 (cols 80 + 4 pad)
  __shared__ __align__(16) float ssin[44][76];    // sino, halo 6
  __shared__ __align__(16) float sx[44][76];      // x, halo 6
  __shared__ __align__(16) float rbuf[40][76];    // p0 on extended region (+pad 0)
  __shared__ float bandv[256];
  __shared__ float Gs[81], kas[25], kws[36];
  __shared__ float red[12];
  const int tid = threadIdx.x;
  const int bimg = blockIdx.z;
  const int oy0 = blockIdx.y*32, ox0 = blockIdx.x*64;
  if (tid < 81) Gs[tid] = tab[972 + tid];
  if (tid >= 81 && tid < 106) kas[tid-81] = Ka[tid-81];
  if (tid >= 106 && tid < 142) kws[tid-106] = Kw[tid-106];
  const float mu = miu[0], lam = laam[0];
  const float* sxk = xk + (size_t)bimg*IMG;
  const float* ssi = sino + (size_t)bimg*IMG;
  const float* sxi = x + (size_t)bimg*IMG;

  for (int i = tid; i < 48*84; i += 256) {
    int ly = i/84, lx = i - 84*ly;
    int gy = oy0+ly-8, gx = ox0+lx-8;
    bool in = (lx < 80) && (unsigned)gy < HH && (unsigned)gx < WW;
    ssrcX[ly][lx] = in ? sxk[gy*WW+gx] : 0.f;
  }
  for (int i = tid; i < 44*76; i += 256) {
    int ly = i/76, lx = i - 76*ly;
    int gy = oy0+ly-6, gx = ox0+lx-6;
    bool in = (unsigned)gy < HH && (unsigned)gx < WW;
    ssin[ly][lx] = in ? ssi[gy*WW+gx] : 0.f;
    sx[ly][lx]   = in ? sxi[gy*WW+gx] : 0.f;
  }
  for (int i = tid; i < 40*76; i += 256) (&rbuf[0][0])[i] = 0.f;
  __syncthreads();

  // ---- A: rbuf = -M(xk) on extended 40x72 (9 chunks of 8 per row) ----
  #pragma unroll 1
  for (int task = tid; task < 360; task += 256) {
    int ry = task/9, rx0 = (task - 9*(task/9))*8;
    float acc[8];
    #pragma unroll
    for (int k = 0; k < 8; k++) acc[k] = 0.f;
    #pragma unroll 1
    for (int t = 0; t < 9; t++) {
      float g[9];
      #pragma unroll
      for (int u = 0; u < 9; u++) g[u] = Gs[t*9+u];
      const float* row = &ssrcX[ry+t][rx0];
      float4 r0 = *(const float4*)(row);
      float4 r1 = *(const float4*)(row+4);
      float4 r2 = *(const float4*)(row+8);
      float4 r3 = *(const float4*)(row+12);
      float v[16] = {r0.x,r0.y,r0.z,r0.w, r1.x,r1.y,r1.z,r1.w,
                     r2.x,r2.y,r2.z,r2.w, r3.x,r3.y,r3.z,r3.w};
      #pragma unroll
      for (int k = 0; k < 8; k++) {
        float a = acc[k];
        #pragma unroll
        for (int u = 0; u < 9; u++) a = fmaf(g[u], v[k+u], a);
        acc[k] = a;
      }
    }
    int gy = oy0 + ry - 4;
    #pragma unroll
    for (int k = 0; k < 8; k++) {
      int gx = ox0 + rx0 + k - 4;
      bool in = ((unsigned)gy < HH) && ((unsigned)gx < WW);
      float val = acc[k];
      if (in && ((gy < 2) | (gy >= HH-2) | (gx < 2) | (gx >= WW-2))) {
        int ty = (gy == 0) ? 0 : (gy == 1) ? 1 : (gy == HH-1) ? 4 : (gy == HH-2) ? 3 : 2;
        int tx = (gx == 0) ? 0 : (gx == 1) ? 1 : (gx == WW-1) ? 4 : (gx == WW-2) ? 3 : 2;
        const float* S = tab + (ty*5 + tx)*81;
        float a = 0.f;
        for (int t = 0; t < 9; t++)
          for (int u = 0; u < 9; u++)
            a = fmaf(S[t*9+u], ssrcX[ry+t][rx0+k+u], a);
        val = a;
      }
      rbuf[ry][rx0+k] = in ? -val : 0.f;
    }
  }

  // ---- B: rbuf += ATop(sino) (same chunk ownership -> no sync needed) ----
  #pragma unroll 1
  for (int task = tid; task < 360; task += 256) {
    int ry = task/9, rx0 = (task - 9*(task/9))*8;
    float acc[8];
    #pragma unroll
    for (int k = 0; k < 8; k++) acc[k] = 0.f;
    #pragma unroll
    for (int dy = 0; dy < 5; dy++) {
      const float* row = &ssin[ry+4-dy][rx0];
      float4 r0 = *(const float4*)(row);
      float4 r1 = *(const float4*)(row+4);
      float4 r2 = *(const float4*)(row+8);
      float w[12] = {r0.x,r0.y,r0.z,r0.w, r1.x,r1.y,r1.z,r1.w, r2.x,r2.y,r2.z,r2.w};
      #pragma unroll
      for (int k = 0; k < 8; k++)
        #pragma unroll
        for (int dx = 0; dx < 5; dx++)
          acc[k] = fmaf(kas[dy*5+dx], w[k+4-dx], acc[k]);
    }
    int gy = oy0 + ry - 4;
    #pragma unroll
    for (int k = 0; k < 8; k++) {
      int gx = ox0 + rx0 + k - 4;
      if (((unsigned)gy < HH) && ((unsigned)gx < WW))
        rbuf[ry][rx0+k] += acc[k];
    }
  }

  // ---- per channel: dnz into tb (alias ssrcX, dead), then mu*WTop into rbuf ----
  float* tb = &ssrcX[0][0];   // 42 x 74 stored at stride 76 (4032 floats available)
  #pragma unroll 1
  for (int ch = 0; ch < 4; ch++) {
    __syncthreads();
    {
      float kw[9];
      #pragma unroll
      for (int k = 0; k < 9; k++) kw[k] = kws[ch*9 + k];
      #pragma unroll 1
      for (int i = tid; i < 42*74; i += 256) {
        int qy = i/74, qx = i - 74*qy;
        int gy = oy0 + qy - 5, gx = ox0 + qx - 5;
        float v = 0.f;
        if (((unsigned)gy < HH) && ((unsigned)gx < WW)) {
          float wu = 0.f;
          #pragma unroll
          for (int e = 0; e < 9; e++) wu = fmaf(kw[e], sx[qy + e/3][qx + e%3], wu);
          v = fmaxf(wu - lam, 0.f) - fmaxf(-wu - lam, 0.f);
        }
        tb[qy*76 + qx] = v;
      }
    }
    __syncthreads();
    {
      float kwm[9];
      #pragma unroll
      for (int k = 0; k < 9; k++) kwm[k] = mu * kws[ch*9 + k];
      #pragma unroll 1
      for (int task = tid; task < 360; task += 256) {
        int ry = task/9, rx0 = (task - 9*(task/9))*8;
        float acc[8];
        #pragma unroll
        for (int k = 0; k < 8; k++) acc[k] = 0.f;
        #pragma unroll
        for (int dy = 0; dy < 3; dy++) {
          const float* row = &tb[(ry+2-dy)*76 + rx0];
          float4 r0 = *(const float4*)(row);
          float4 r1 = *(const float4*)(row+4);
          float4 r2 = *(const float4*)(row+8);
          float w[12] = {r0.x,r0.y,r0.z,r0.w, r1.x,r1.y,r1.z,r1.w, r2.x,r2.y,r2.z,r2.w};
          #pragma unroll
          for (int k = 0; k < 8; k++)
            #pragma unroll
            for (int dx = 0; dx < 3; dx++)
              acc[k] = fmaf(kwm[dy*3+dx], w[k+2-dx], acc[k]);
        }
        int gy = oy0 + ry - 4;
        #pragma unroll
        for (int k = 0; k < 8; k++) {
          int gx = ox0 + rx0 + k - 4;
          if (((unsigned)gy < HH) && ((unsigned)gx < WW))
            rbuf[ry][rx0+k] += acc[k];
        }
      }
    }
  }
  __syncthreads();

  // ---- outputs: p0 = rbuf, r = -p0, q0 = M(p0); reduce den/rq/qq/rtr ----
  const int sy = tid >> 3, sx0v = (tid & 7)*8;
  const size_t base = (size_t)bimg*IMG + (size_t)(oy0+sy)*WW + ox0 + sx0v;
  float p8[8];
  float rtr = 0.f;
  #pragma unroll
  for (int k = 0; k < 8; k++) {
    p8[k] = rbuf[sy+4][sx0v+4+k];
    rtr += p8[k]*p8[k];
  }
  *(float4*)&outP[base]   = make_float4(p8[0], p8[1], p8[2], p8[3]);
  *(float4*)&outP[base+4] = make_float4(p8[4], p8[5], p8[6], p8[7]);
  *(float4*)&outR[base]   = make_float4(-p8[0], -p8[1], -p8[2], -p8[3]);
  *(float4*)&outR[base+4] = make_float4(-p8[4], -p8[5], -p8[6], -p8[7]);

  float q8[8];
  apply_M2(rbuf, bandv, Gs, tab, tid, oy0, ox0, q8);
  float den = 0.f, qq = 0.f;
  #pragma unroll
  for (int k = 0; k < 8; k++) {
    den += p8[k]*q8[k];
    qq  += q8[k]*q8[k];
  }
  *(float4*)&outQ[base]   = make_float4(q8[0], q8[1], q8[2], q8[3]);
  *(float4*)&outQ[base+4] = make_float4(q8[4], q8[5], q8[6], q8[7]);

  reduce3_atomic(den, qq, rtr, red, &scal[bimg], &scal[96+bimg], &scal[144+bimg]);
  if (tid == 0)
    atomicAdd(&scal[48+bimg], -(red[0]+red[3]+red[6]+red[9]));  // rq0 = -den0
}

// ---------------- fused CG iteration (scalar recurrence) ---------------------------
__launch_bounds__(256)
__global__ void k_it(float* __restrict__ xk,
                     const float* __restrict__ rold, float* __restrict__ rnew,
                     const float* __restrict__ pold, float* __restrict__ pnew,
                     const float* __restrict__ qold, float* __restrict__ qnew,
                     const float* __restrict__ tab,
                     float* __restrict__ scal, int it, int storeQ) {
  __shared__ __align__(16) float ssrc[40][76];
  __shared__ float rlds[2048];
  __shared__ float bandv[256];
  __shared__ float Gs[81];
  __shared__ float red[12];
  const int tid = threadIdx.x;
  const int bimg = blockIdx.z;
  const int oy0 = blockIdx.y*32, ox0 = blockIdx.x*64;
  if (tid < 81) Gs[tid] = tab[972 + tid];
  const float den_p = scal[       (it-1)*8 + bimg];
  const float rq_p  = scal[ 48 + (it-1)*8 + bimg];
  const float qq_p  = scal[ 96 + (it-1)*8 + bimg];
  const float rtr_p = scal[144 + (it-1)*8 + bimg];
  const float al = rtr_p / den_p;
  const float rtr_c = fmaf(al, fmaf(al, qq_p, 2.f*rq_p), rtr_p);
  const float be = rtr_c / rtr_p;
  if (tid == 0) scal[144 + it*8 + bimg] = rtr_c;
  const size_t ib = (size_t)bimg*IMG;

  for (int i = tid; i < 40*76; i += 256) {
    int ly = i/76, lx = i%76;
    int gy = oy0 + ly - 4, gx = ox0 + lx - 4;
    bool in = (lx < 72) && (gy >= 0 && gy < HH && gx >= 0 && gx < WW);
    float v = 0.f;
    if (in) {
      size_t g = ib + (size_t)gy*WW + gx;
      float pgv = pold[g];
      float rn = fmaf(al, qold[g], rold[g]);
      v = fmaf(be, pgv, -rn);
      if (ly >= 4 && ly < 36 && lx >= 4 && lx < 68) {
        pnew[g] = v;
        rnew[g] = rn;
        xk[g] = fmaf(al, pgv, xk[g]);
        rlds[(ly-4)*64 + (lx-4)] = rn;
      }
    }
    ssrc[ly][lx] = v;
  }
  __syncthreads();

  float accv[8];
  apply_M2(ssrc, bandv, Gs, tab, tid, oy0, ox0, accv);

  const int sy = tid >> 3, sx0 = (tid & 7) * 8;
  const int gy = oy0 + sy, gx0 = ox0 + sx0;
  float s_den = 0.f, s_rq = 0.f, s_qq = 0.f;
  #pragma unroll
  for (int k = 0; k < 8; k++) {
    size_t idx = ib + (size_t)gy*WW + gx0 + k;
    float qv = accv[k];
    float pv = ssrc[sy+4][sx0+4+k];
    float rv = rlds[sy*64 + sx0 + k];
    if (storeQ) qnew[idx] = qv;
    s_den += pv*qv;
    s_rq  += rv*qv;
    s_qq  += qv*qv;
  }
  reduce3_atomic(s_den, s_rq, s_qq, red, &scal[it*8+bimg], &scal[48+it*8+bimg],
                 &scal[96+it*8+bimg]);
}

__launch_bounds__(256)
__global__ void k_final(const float* __restrict__ xk, const float* __restrict__ p,
                        const float* __restrict__ num, const float* __restrict__ den,
                        float* __restrict__ out) {
  const int tid = threadIdx.x;
  const int bimg = blockIdx.x >> 8;
  const size_t idx4 = (size_t)blockIdx.x * 256 + tid;
  const float al = num[bimg] / den[bimg];
  float4 xv = ((const float4*)xk)[idx4];
  float4 pv = ((const float4*)p)[idx4];
  float4 o;
  o.x = xv.x + al*pv.x; o.y = xv.y + al*pv.y; o.z = xv.z + al*pv.z; o.w = xv.w + al*pv.w;
  ((float4*)out)[idx4] = o;
}

extern "C" void kernel_launch(void* const* d_in, const int* in_sizes, int n_in,
                              void* d_out, int out_size, void* d_ws, size_t ws_size,
                              hipStream_t stream) {
  const float* sino = (const float*)d_in[0];
  const float* x    = (const float*)d_in[1];
  const float* laam = (const float*)d_in[2];
  const float* miu  = (const float*)d_in[3];
  const float* Kw   = (const float*)d_in[4];
  const float* Ka   = (const float*)d_in[5];
  const float* W1   = (const float*)d_in[6];
  const float* b1   = (const float*)d_in[7];
  const float* W2   = (const float*)d_in[8];
  const float* b2   = (const float*)d_in[9];
  const float* W3   = (const float*)d_in[10];
  const float* b3   = (const float*)d_in[11];

  float* ws = (float*)d_ws;
  float* tail = ws + (size_t)6*NTOT;
  float* tab  = tail;                  // 2025 (pad 2048)
  float* scal = tail + 2048;           // 192: den[48] rq[48] qq[48] rtr[48]
  ushort* w2pk = (ushort*)(scal + 192);
  uint*   w1pk = (uint*)(w2pk + 9216);
  uint*   b1pk = w1pk + 144;
  ushort* w3fr = (ushort*)(b1pk + 16);
  float* dout = (float*)d_out;

  k_prep<<<1, 1024, 0, stream>>>(Ka, Kw, miu, W1, b1, W2, W3, tab, w2pk, w1pk,
                                 b1pk, w3fr, scal);

  float* xk = ws;
  k_cnn<<<dim3(32,32,8), 512, 0, stream>>>(x, w2pk, w1pk, b1pk, w3fr, b2, b3, xk);

  dim3 mg(8,16,8);
  float* rA = ws + (size_t)NTOT;
  float* rB = ws + 2*(size_t)NTOT;
  float* pA = ws + 3*(size_t)NTOT;
  float* pB = ws + 4*(size_t)NTOT;
  float* qB = ws + 5*(size_t)NTOT;
  float* qA = dout;
  k_M01<<<mg,256,0,stream>>>(xk, sino, x, rA, pA, qA, tab, Ka, Kw, laam, miu, scal);
  float *rc=rA, *rn=rB, *pc=pA, *pn=pB, *qc=qA, *qn=qB;
  for (int it = 1; it <= 5; it++) {
    k_it<<<mg,256,0,stream>>>(xk, rc, rn, pc, pn, qc, qn, tab, scal,
                              it, it < 5 ? 1 : 0);
    float* t;
    t = rc; rc = rn; rn = t;
    t = pc; pc = pn; pn = t;
    t = qc; qc = qn; qn = t;
  }
  k_final<<<2048,256,0,stream>>>(xk, pc, &scal[144+40], &scal[40], dout);
}

// Round 15
// 363.216 us; speedup vs baseline: 1.1520x; 1.1520x over previous
//
#include <hip/hip_runtime.h>

#define HH 512
#define WW 512
#define BB 8
#define IMG (HH*WW)
#define NTOT (BB*IMG)

typedef float f32x4 __attribute__((ext_vector_type(4)));
typedef _Float16 half8 __attribute__((ext_vector_type(8)));

__device__ inline uint f2h2(float a, float b) {
  uint d; asm("v_cvt_pkrtz_f16_f32 %0, %1, %2" : "=v"(d) : "v"(a), "v"(b)); return d;
}
__device__ inline uint pkfma(uint a, uint b, uint c) {
  uint d; asm("v_pk_fma_f16 %0, %1, %2, %3" : "=v"(d) : "v"(a), "v"(b), "v"(c)); return d;
}
__device__ inline uint pkmax0(uint a) {
  uint d, z = 0u; asm("v_pk_max_f16 %0, %1, %2" : "=v"(d) : "v"(a), "v"(z)); return d;
}

__device__ inline void atomic_block_sum(float part, float* red, float* dst) {
  for (int off = 32; off > 0; off >>= 1) part += __shfl_down(part, off, 64);
  int lane = threadIdx.x & 63, w = threadIdx.x >> 6;
  if (lane == 0) red[w] = part;
  __syncthreads();
  if (threadIdx.x == 0) atomicAdd(dst, red[0] + red[1] + red[2] + red[3]);
}

__device__ inline void reduce3_atomic(float a, float b, float c, float* red,
                                      float* da, float* db, float* dc) {
  for (int off = 32; off > 0; off >>= 1) {
    a += __shfl_down(a, off, 64);
    b += __shfl_down(b, off, 64);
    c += __shfl_down(c, off, 64);
  }
  int lane = threadIdx.x & 63, w = threadIdx.x >> 6;
  if (lane == 0) { red[w*3] = a; red[w*3+1] = b; red[w*3+2] = c; }
  __syncthreads();
  if (threadIdx.x == 0) {
    atomicAdd(da, red[0]+red[3]+red[6]+red[9]);
    if (db) atomicAdd(db, red[1]+red[4]+red[7]+red[10]);
    if (dc) atomicAdd(dc, red[2]+red[5]+red[8]+red[11]);
  }
}

// masks for boundary-corrected stencils: t = 0(row0),1(row1),2(interior),3(H-2),4(H-1)
__device__ inline bool mA5(int t, int e) {
  return (t==0) ? (e<=2) : (t==1) ? (e<=3) : (t==3) ? (e>=1) : (t==4) ? (e>=2) : true;
}
__device__ inline bool mW3(int t, int e) {
  return (t==0) ? (e<=1) : (t==4) ? (e>=1) : true;
}

// ---------------- prep: scalars, 25x81 stencil table, fp16 weight packing ----------
__global__ void k_prep(const float* __restrict__ Ka, const float* __restrict__ Kw,
                       const float* __restrict__ miu,
                       const float* __restrict__ W1, const float* __restrict__ b1,
                       const float* __restrict__ W2, const float* __restrict__ W3,
                       float* __restrict__ tab, ushort* __restrict__ w2pk,
                       uint* __restrict__ w1pk, uint* __restrict__ b1pk,
                       ushort* __restrict__ w3fr, float* __restrict__ scal) {
  __shared__ float lka[25], lkw[36], lw1[288], lw3[288];
  int tid = threadIdx.x;   // 1024 threads
  if (tid < 192) scal[tid] = 0.f;
  if (tid < 25) lka[tid] = Ka[tid];
  if (tid < 36) lkw[tid] = Kw[tid];
  if (tid < 288) { lw1[tid] = W1[tid]; lw3[tid] = W3[tid]; }
  __syncthreads();
  const float mu = miu[0];
  #pragma unroll
  for (int k = 0; k < 2; k++) {
    int idx = tid + k*1024;
    if (idx < 2025) {
      int c = idx / 81, o = idx - c*81;
      int ty = c / 5, tx = c - 5*ty;
      int uy = o / 9 - 4, ux = o % 9 - 4;
      float s = 0.f;
      for (int ey = 0; ey < 5; ey++)
        for (int ex = 0; ex < 5; ex++) {
          int dy = ey + uy, dx = ex + ux;
          if (dy >= 0 && dy < 5 && dx >= 0 && dx < 5 && mA5(ty,ey) && mA5(tx,ex))
            s += lka[ey*5+ex] * lka[dy*5+dx];
        }
      float sw = 0.f;
      for (int ch = 0; ch < 4; ch++)
        for (int ey = 0; ey < 3; ey++)
          for (int ex = 0; ex < 3; ex++) {
            int dy = ey + uy, dx = ex + ux;
            if (dy >= 0 && dy < 3 && dx >= 0 && dx < 3 && mW3(ty,ey) && mW3(tx,ex))
              sw += lkw[ch*9+ey*3+ex] * lkw[ch*9+dy*3+dx];
          }
      tab[idx] = s + mu * sw;
    }
  }
  #pragma unroll
  for (int k = 0; k < 9; k++) {
    int i = tid + k*1024;
    int j = i & 7, l = (i >> 3) & 63, f = i >> 9;
    int t5 = f >> 1, h = f & 1;
    int co = 16*h + (l & 15), ci = 8*(l >> 4) + j;
    w2pk[i] = (ushort)(f2h2(W2[(co*32 + ci)*9 + t5], 0.f) & 0xffffu);
  }
  if (tid < 144) {
    int cp = tid / 9, t = tid % 9;
    w1pk[tid] = f2h2(lw1[(2*cp)*9 + t], lw1[(2*cp+1)*9 + t]);
  }
  if (tid < 16) b1pk[tid] = f2h2(b1[2*tid], b1[2*tid+1]);
  if (tid < 512) {
    int j = tid & 7, l = tid >> 3;
    int tap = l & 15, ch = 8*(l >> 4) + j;
    w3fr[tid] = (tap < 9) ? (ushort)(f2h2(lw3[ch*9 + tap], 0.f) & 0xffffu) : (ushort)0;
  }
}

// ---------------- fused CNN: xk = cnn(x), fp16/MFMA --------------------------------
__launch_bounds__(512, 2)
__global__ void k_cnn(const float* __restrict__ x,
                      const ushort* __restrict__ w2pk, const uint* __restrict__ w1pk,
                      const uint* __restrict__ b1pk, const ushort* __restrict__ w3fr,
                      const float* __restrict__ b2, const float* __restrict__ b3,
                      float* __restrict__ xk) {
  __shared__ __align__(16) uint  h1u[7040];         // 20 x 352
  __shared__ __align__(16) uint  h2u[5472];         // 18 x 304; head doubles as xs
  uint* xs_h2 = h2u;

  const int tid = threadIdx.x;
  const int bimg = blockIdx.z;
  const int oy0 = blockIdx.y * 16, ox0 = blockIdx.x * 16;
  const float* xim = x + (size_t)bimg * IMG;

  for (int i = tid; i < 528; i += 512) {
    int ly = i / 24, lx = i % 24;
    int gy = oy0 + ly - 3, gx = ox0 + lx - 4;
    float v = 0.f;
    if ((unsigned)gy < HH && (unsigned)gx < WW) v = xim[gy*WW + gx];
    xs_h2[i] = f2h2(v, v);
  }
  __syncthreads();

  // ---- conv1 ----
  {
    const int cp = tid & 15;
    const int sg = tid >> 4;
    uint w1r[9];
    #pragma unroll
    for (int k = 0; k < 9; k++) w1r[k] = w1pk[cp*9 + k];
    const uint b1v = b1pk[cp];
    const int kg = cp >> 2, cl = cp & 3;
    #pragma unroll 1
    for (int s = sg; s < 100; s += 32) {
      int row = s / 5, st = s - 5*row;
      int px0 = st * 4;
      uint acc0 = b1v, acc1 = b1v, acc2 = b1v, acc3 = b1v;
      #pragma unroll
      for (int ky = 0; ky < 3; ky++) {
        int base = (row + ky) * 24 + px0;
        uint4 xa = *(const uint4*)&xs_h2[base];
        uint4 xb = *(const uint4*)&xs_h2[base + 4];
        uint xu[8] = {xa.x, xa.y, xa.z, xa.w, xb.x, xb.y, xb.z, xb.w};
        #pragma unroll
        for (int kx = 0; kx < 3; kx++) {
          uint w = w1r[ky*3 + kx];
          acc0 = pkfma(w, xu[1 + kx], acc0);
          acc1 = pkfma(w, xu[2 + kx], acc1);
          acc2 = pkfma(w, xu[3 + kx], acc2);
          acc3 = pkfma(w, xu[4 + kx], acc3);
        }
      }
      int Y = oy0 + row - 2;
      bool rin = (unsigned)Y < HH;
      int ob = row*352 + kg*88 + px0*4 + cl;
      #pragma unroll
      for (int i = 0; i < 4; i++) {
        int X = ox0 + px0 + i - 2;
        uint v = (rin && (unsigned)X < WW) ?
                 pkmax0(i == 0 ? acc0 : (i == 1 ? acc1 : (i == 2 ? acc2 : acc3))) : 0u;
        h1u[ob + i*4] = v;
      }
    }
  }
  __syncthreads();

  // ---- conv2 via MFMA f16 ----
  const int wv = tid >> 6, lane = tid & 63;
  const int nn = lane & 15, kg = lane >> 4;
  {
    half8 afr[9][2];
    #pragma unroll
    for (int t5 = 0; t5 < 9; t5++) {
      afr[t5][0] = ((const half8*)w2pk)[(t5*2 + 0)*64 + lane];
      afr[t5][1] = ((const half8*)w2pk)[(t5*2 + 1)*64 + lane];
    }
    float b2A[4], b2B[4];
    #pragma unroll
    for (int j = 0; j < 4; j++) { b2A[j] = b2[4*kg + j]; b2B[j] = b2[16 + 4*kg + j]; }

    #pragma unroll 1
    for (int t = wv; t < 27; t += 8) {
      int rp = t / 3, cs = t - 3*rp;
      int tx0 = (cs == 2) ? 10 : (cs << 3);
      int brow = 2*rp + (nn >> 3);
      int bcol = tx0 + (nn & 7);
      f32x4 accA = {0.f,0.f,0.f,0.f}, accB = {0.f,0.f,0.f,0.f};
      #pragma unroll
      for (int ky = 0; ky < 3; ky++)
        #pragma unroll
        for (int kx = 0; kx < 3; kx++) {
          const half8 bfr = *(const half8*)&h1u[(brow+ky)*352 + kg*88 + (bcol+kx)*4];
          accA = __builtin_amdgcn_mfma_f32_16x16x32_f16(afr[ky*3+kx][0], bfr, accA, 0, 0, 0);
          accB = __builtin_amdgcn_mfma_f32_16x16x32_f16(afr[ky*3+kx][1], bfr, accB, 0, 0, 0);
        }
      int gy = oy0 + brow - 1, gx = ox0 + bcol - 1;
      bool inb = ((unsigned)gy < HH) && ((unsigned)gx < WW);
      float v0 = inb ? fmaxf(accA[0] + b2A[0], 0.f) : 0.f;
      float v1 = inb ? fmaxf(accA[1] + b2A[1], 0.f) : 0.f;
      float v2 = inb ? fmaxf(accA[2] + b2A[2], 0.f) : 0.f;
      float v3 = inb ? fmaxf(accA[3] + b2A[3], 0.f) : 0.f;
      uint2 uA = make_uint2(f2h2(v0, v1), f2h2(v2, v3));
      v0 = inb ? fmaxf(accB[0] + b2B[0], 0.f) : 0.f;
      v1 = inb ? fmaxf(accB[1] + b2B[1], 0.f) : 0.f;
      v2 = inb ? fmaxf(accB[2] + b2B[2], 0.f) : 0.f;
      v3 = inb ? fmaxf(accB[3] + b2B[3], 0.f) : 0.f;
      uint2 uB = make_uint2(f2h2(v0, v1), f2h2(v2, v3));
      int base = brow*304 + bcol*4 + (kg & 1)*2;
      *(uint2*)&h2u[base + (kg >> 1)*76]       = uA;
      *(uint2*)&h2u[base + (2 + (kg >> 1))*76] = uB;
    }
  }
  __syncthreads();

  // ---- conv3 stage 1 via MFMA (Tlds aliased onto dead h1u) ----
  float* Tlds = (float*)h1u;
  {
    const half8 w3f = ((const half8*)w3fr)[lane];
    const int tap = nn;
    #pragma unroll 1
    for (int t = wv; t < 27; t += 8) {
      int rp = t / 3, cs = t - 3*rp;
      int tx0 = (cs == 2) ? 10 : (cs << 3);
      int ay = 2*rp + (nn >> 3);
      int ax = tx0 + (nn & 7);
      const half8 afrag = *(const half8*)&h2u[ay*304 + kg*76 + ax*4];
      f32x4 z = {0.f,0.f,0.f,0.f};
      f32x4 T4 = __builtin_amdgcn_mfma_f32_16x16x32_f16(afrag, w3f, z, 0, 0, 0);
      if (tap < 9) {
        int ty = 2*rp + (kg >> 1);
        int txb = tx0 + 4*(kg & 1);
        float* dst = &Tlds[ty*180 + tap*20 + txb];
        if (cs == 2) {
          dst[0] = T4[0]; dst[1] = T4[1]; dst[2] = T4[2]; dst[3] = T4[3];
        } else {
          *(f32x4*)dst = T4;
        }
      }
    }
  }
  __syncthreads();

  // ---- conv3 gather + residual ----
  {
    const int half = tid & 1, px = tid >> 1;
    const int oy = px >> 4, ox = px & 15;
    float s = 0.f;
    if (half == 0) {
      #pragma unroll
      for (int t = 0; t < 4; t++)
        s += Tlds[(oy + t/3)*180 + t*20 + (ox + t%3)];
    } else {
      #pragma unroll
      for (int t = 4; t < 9; t++)
        s += Tlds[(oy + t/3)*180 + t*20 + (ox + t%3)];
    }
    float other = __shfl_xor(s, 1, 64);
    if (half == 0) {
      float tot = s + other + b3[0] + xim[(size_t)(oy0+oy)*WW + ox0 + ox];
      xk[(size_t)bimg*IMG + (size_t)(oy0+oy)*WW + ox0 + ox] = tot;
    }
  }
}

// ---------------- M-apply: G-stencil + table-corrected boundary band ---------------
__device__ __forceinline__ void apply_M2(const float (*ssrc)[76], float* bandv,
    const float* Gs, const float* __restrict__ tab,
    int tid, int oy0, int ox0, float* accv) {
  const int sy = tid >> 3, sx0 = (tid & 7) * 8;
  #pragma unroll
  for (int k = 0; k < 8; k++) accv[k] = 0.f;
  #pragma unroll 1
  for (int oyy = 0; oyy < 9; oyy++) {
    float g[9];
    #pragma unroll
    for (int t = 0; t < 9; t++) g[t] = Gs[oyy*9+t];
    const float* row = &ssrc[sy+oyy][sx0];
    float4 r0 = *(const float4*)(row);
    float4 r1 = *(const float4*)(row+4);
    float4 r2 = *(const float4*)(row+8);
    float4 r3 = *(const float4*)(row+12);
    float v[16] = {r0.x,r0.y,r0.z,r0.w, r1.x,r1.y,r1.z,r1.w,
                   r2.x,r2.y,r2.z,r2.w, r3.x,r3.y,r3.z,r3.w};
    #pragma unroll
    for (int k = 0; k < 8; k++) {
      float a = accv[k];
      #pragma unroll
      for (int t = 0; t < 9; t++) a = fmaf(g[t], v[k+t], a);
      accv[k] = a;
    }
  }
  const int by = blockIdx.y, bx = blockIdx.x;
  const bool eT = (by == 0), eB = (by == (int)gridDim.y - 1);
  const bool eL = (bx == 0), eR = (bx == (int)gridDim.x - 1);
  if (eT | eB | eL | eR) {
    const int nTop = eT ? 128 : 0;
    const int nBot = eB ? 128 : 0;
    const int yl = eT ? 2 : 0, yh = eB ? 30 : 32;
    const int nL = eL ? 2*(yh-yl) : 0;
    const int nR = eR ? 2*(yh-yl) : 0;
    const int nBand = nTop + nBot + nL + nR;
    if (tid < nBand) {
      int i = tid, bsy, bsx;
      if (i < nTop) { bsy = i >> 6; bsx = i & 63; }
      else if (i < nTop + nBot) { i -= nTop; bsy = 30 + (i >> 6); bsx = i & 63; }
      else if (i < nTop + nBot + nL) { i -= nTop + nBot; bsy = yl + (i >> 1); bsx = i & 1; }
      else { i -= nTop + nBot + nL; bsy = yl + (i >> 1); bsx = 62 + (i & 1); }
      const int gy = oy0 + bsy, gx = ox0 + bsx;
      int ty = (gy == 0) ? 0 : (gy == 1) ? 1 : (gy == HH-1) ? 4 : (gy == HH-2) ? 3 : 2;
      int tx = (gx == 0) ? 0 : (gx == 1) ? 1 : (gx == WW-1) ? 4 : (gx == WW-2) ? 3 : 2;
      const float* S = tab + (ty*5 + tx)*81;
      float a = 0.f;
      #pragma unroll
      for (int oy = 0; oy < 9; oy++) {
        const float* r = &ssrc[bsy+oy][bsx];
        #pragma unroll
        for (int ox = 0; ox < 9; ox++) a = fmaf(S[oy*9+ox], r[ox], a);
      }
      bandv[tid] = a;
    }
    __syncthreads();
    #pragma unroll
    for (int k = 0; k < 8; k++) {
      const int sx = sx0 + k;
      const int gy = oy0 + sy, gx = ox0 + sx;
      if ((gy < 2) || (gy >= HH-2) || (gx < 2) || (gx >= WW-2)) {
        int idx;
        if (eT && sy < 2) idx = sy*64 + sx;
        else if (eB && sy >= 30) idx = nTop + (sy-30)*64 + sx;
        else if (eL && sx < 2) idx = nTop + nBot + (sy-yl)*2 + sx;
        else idx = nTop + nBot + nL + (sy-yl)*2 + (sx-62);
        accv[k] = bandv[idx];
      }
    }
  }
}

// ---------------- k_M0: fused rhs + r = M(xk) - rhs, p = -r, rtr reduction ---------
__launch_bounds__(256)
__global__ void k_M0(const float* __restrict__ xk, const float* __restrict__ sino,
                     const float* __restrict__ x,
                     float* __restrict__ outR, float* __restrict__ outP,
                     const float* __restrict__ tab,
                     const float* __restrict__ Ka, const float* __restrict__ Kw,
                     const float* __restrict__ laam, const float* __restrict__ miu,
                     float* __restrict__ rtrOut) {
  __shared__ __align__(16) float ssrc[40][76];
  __shared__ __align__(16) float tbuf[36][68];
  __shared__ __align__(16) float ssin[36][68];
  __shared__ __align__(16) float sx[36][68];
  __shared__ float Gs[81], kas[25], kws[36];
  __shared__ float red[4];
  const int tid = threadIdx.x;
  const int bimg = blockIdx.z;
  const int oy0 = blockIdx.y*32, ox0 = blockIdx.x*64;
  if (tid < 81) Gs[tid] = tab[972 + tid];
  if (tid >= 81 && tid < 106) kas[tid-81] = Ka[tid-81];
  if (tid >= 106 && tid < 142) kws[tid-106] = Kw[tid-106];
  const float mu = miu[0];
  const float lam = laam[0];
  const float* sxk = xk + (size_t)bimg*IMG;
  const float* ssi = sino + (size_t)bimg*IMG;
  const float* sxi = x + (size_t)bimg*IMG;

  for (int i = tid; i < 40*76; i += 256) {
    int ly = i/76, lx = i%76;
    int gy = oy0 + ly - 4, gx = ox0 + lx - 4;
    bool in = (lx < 72) && (gy >= 0 && gy < HH && gx >= 0 && gx < WW);
    ssrc[ly][lx] = in ? sxk[gy*WW+gx] : 0.f;
  }
  for (int i = tid; i < 36*68; i += 256) {
    int ly = i/68, lx = i%68;
    int gy = oy0 + ly - 2, gx = ox0 + lx - 2;
    bool in = (gy >= 0 && gy < HH && gx >= 0 && gx < WW);
    ssin[ly][lx] = in ? ssi[gy*WW+gx] : 0.f;
    sx[ly][lx]   = in ? sxi[gy*WW+gx] : 0.f;
  }
  __syncthreads();

  float accv[8];
  apply_M2(ssrc, &tbuf[0][0], Gs, tab, tid, oy0, ox0, accv);

  const int sy = tid >> 3, sx0 = (tid & 7) * 8;
  float rhsv[8];
  #pragma unroll
  for (int k = 0; k < 8; k++) rhsv[k] = 0.f;
  {
    #pragma unroll
    for (int dy = 0; dy < 5; dy++) {
      const float* row = &ssin[sy+4-dy][sx0];
      float4 r0 = *(const float4*)(row);
      float4 r1 = *(const float4*)(row+4);
      float4 r2 = *(const float4*)(row+8);
      float w[12] = {r0.x,r0.y,r0.z,r0.w, r1.x,r1.y,r1.z,r1.w, r2.x,r2.y,r2.z,r2.w};
      #pragma unroll
      for (int k = 0; k < 8; k++)
        #pragma unroll
        for (int dx = 0; dx < 5; dx++)
          rhsv[k] = fmaf(kas[dy*5+dx], w[k+4-dx], rhsv[k]);
    }
  }
  #pragma unroll 1
  for (int ch = 0; ch < 4; ch++) {
    __syncthreads();
    {
      float kw[9];
      #pragma unroll
      for (int k = 0; k < 9; k++) kw[k] = kws[ch*9 + k];
      #pragma unroll 1
      for (int item = tid; item < 2244; item += 256) {
        int dy = item / 66, dx = item - 66*dy;
        int gy = oy0 + dy - 1, gx = ox0 + dx - 1;
        float v = 0.f;
        if (gy >= 0 && gy < HH && gx >= 0 && gx < WW) {
          float wu = 0.f;
          #pragma unroll
          for (int e = 0; e < 9; e++) wu = fmaf(kw[e], sx[dy + e/3][dx + e%3], wu);
          v = fmaxf(wu - lam, 0.f) - fmaxf(-wu - lam, 0.f);
        }
        tbuf[dy][dx] = v;
      }
    }
    __syncthreads();
    {
      float kw[9];
      #pragma unroll
      for (int k = 0; k < 9; k++) kw[k] = mu * kws[ch*9 + k];
      #pragma unroll
      for (int dy = 0; dy < 3; dy++) {
        const float* row = &tbuf[sy+2-dy][sx0];
        float4 r0 = *(const float4*)(row);
        float4 r1 = *(const float4*)(row+4);
        float4 r2 = *(const float4*)(row+8);
        float w[12] = {r0.x,r0.y,r0.z,r0.w, r1.x,r1.y,r1.z,r1.w, r2.x,r2.y,r2.z,r2.w};
        #pragma unroll
        for (int k = 0; k < 8; k++)
          #pragma unroll
          for (int dx = 0; dx < 3; dx++)
            rhsv[k] = fmaf(kw[dy*3+dx], w[k+2-dx], rhsv[k]);
      }
    }
  }

  const int gy = oy0 + sy, gx0 = ox0 + sx0;
  float part = 0.f;
  #pragma unroll
  for (int k = 0; k < 8; k++) {
    size_t idx = (size_t)bimg*IMG + gy*WW + gx0 + k;
    float rv = accv[k] - rhsv[k];
    outR[idx] = rv;
    outP[idx] = -rv;
    part += rv*rv;
  }
  atomic_block_sum(part, red, &rtrOut[bimg]);
}

// ---------------- k_M: MODE 1 (q0 + den/rq/qq) -------------------------------------
template<int MODE>
__launch_bounds__(256)
__global__ void k_M(const float* __restrict__ srcA, const float* __restrict__ srcB,
                    float* __restrict__ outQ, float* __restrict__ outP,
                    const float* __restrict__ tab,
                    const float* __restrict__ beN, const float* __restrict__ beD,
                    float* __restrict__ acc, float* __restrict__ rqOut,
                    float* __restrict__ qqOut) {
  __shared__ __align__(16) float ssrc[40][76];
  __shared__ float bandv[256];
  __shared__ float Gs[81];
  __shared__ float red[12];
  const int tid = threadIdx.x;
  const int bimg = blockIdx.z;
  const int oy0 = blockIdx.y*32, ox0 = blockIdx.x*64;
  if (tid < 81) Gs[tid] = tab[972 + tid];
  float be = 0.f;
  if (MODE == 2) be = beN[bimg] / beD[bimg];
  const float* sA = srcA + (size_t)bimg*IMG;
  const float* sB = (MODE == 2) ? srcB + (size_t)bimg*IMG : nullptr;

  for (int i = tid; i < 40*76; i += 256) {
    int ly = i/76, lx = i%76;
    int gy = oy0 + ly - 4, gx = ox0 + lx - 4;
    bool in = (lx < 72) && (gy >= 0 && gy < HH && gx >= 0 && gx < WW);
    float v = 0.f;
    if (MODE == 2) {
      if (in) {
        v = -sA[gy*WW+gx] + be * sB[gy*WW+gx];
        if (ly >= 4 && ly < 36 && lx >= 4 && lx < 68)
          outP[(size_t)bimg*IMG + gy*WW + gx] = v;
      }
    } else {
      if (in) v = sA[gy*WW+gx];
    }
    ssrc[ly][lx] = v;
  }
  __syncthreads();

  float accv[8];
  apply_M2(ssrc, bandv, Gs, tab, tid, oy0, ox0, accv);

  const int sy = tid >> 3, sx0 = (tid & 7) * 8;
  const int gy = oy0 + sy, gx0 = ox0 + sx0;
  if (MODE == 1) {
    float pq = 0.f, qq = 0.f;
    #pragma unroll
    for (int k = 0; k < 8; k++) {
      size_t idx = (size_t)bimg*IMG + gy*WW + gx0 + k;
      float pv = ssrc[sy+4][sx0+4+k];
      float qv = accv[k];
      outQ[idx] = qv;
      pq += pv * qv;
      qq += qv * qv;
    }
    reduce3_atomic(pq, -pq, qq, red, &acc[bimg], rqOut ? &rqOut[bimg] : nullptr,
                   qqOut ? &qqOut[bimg] : nullptr);
  } else {
    float part = 0.f;
    #pragma unroll
    for (int k = 0; k < 8; k++) {
      size_t idx = (size_t)bimg*IMG + gy*WW + gx0 + k;
      float pv = ssrc[sy+4][sx0+4+k];
      outQ[idx] = accv[k];
      part += pv * accv[k];
    }
    atomic_block_sum(part, red, &acc[bimg]);
  }
}

// ---------------- fused CG iteration: owner-interior in registers ------------------
__launch_bounds__(256)
__global__ void k_it(float* __restrict__ xk,
                     const float* __restrict__ rold, float* __restrict__ rnew,
                     const float* __restrict__ pold, float* __restrict__ pnew,
                     const float* __restrict__ qold, float* __restrict__ qnew,
                     const float* __restrict__ tab,
                     float* __restrict__ scal, int it, int storeQ) {
  __shared__ __align__(16) float ssrc[40][76];
  __shared__ float bandv[256];
  __shared__ float Gs[81];
  __shared__ float red[12];
  const int tid = threadIdx.x;
  const int bimg = blockIdx.z;
  const int oy0 = blockIdx.y*32, ox0 = blockIdx.x*64;
  if (tid < 81) Gs[tid] = tab[972 + tid];
  const float den_p = scal[       (it-1)*8 + bimg];
  const float rq_p  = scal[ 48 + (it-1)*8 + bimg];
  const float qq_p  = scal[ 96 + (it-1)*8 + bimg];
  const float rtr_p = scal[144 + (it-1)*8 + bimg];
  const float al = rtr_p / den_p;
  const float rtr_c = fmaf(al, fmaf(al, qq_p, 2.f*rq_p), rtr_p);
  const float be = rtr_c / rtr_p;
  if (tid == 0) scal[144 + it*8 + bimg] = rtr_c;
  const size_t ib = (size_t)bimg*IMG;

  // ---- halo frame (992 elems): p_new = be*p - (r + al*q), predicated ----
  for (int i = tid; i < 992; i += 256) {
    int ly, lx;
    if (i < 304) { ly = i/76; lx = i - 76*ly; }
    else if (i < 608) { int j = i-304; int q = j/76; ly = 36 + q; lx = j - 76*q; }
    else { int j = i-608; int q = j/12; ly = 4 + q; int c = j - 12*q; lx = (c < 4) ? c : c + 64; }
    int gy = oy0 + ly - 4, gx = ox0 + lx - 4;
    float v = 0.f;
    if (lx < 72 && (unsigned)gy < HH && (unsigned)gx < WW) {
      size_t g = ib + (size_t)gy*WW + gx;
      v = fmaf(be, pold[g], -fmaf(al, qold[g], rold[g]));
    }
    ssrc[ly][lx] = v;
  }

  // ---- interior by owners: coalesced float4, state kept in registers ----
  const int sy = tid >> 3, sx0 = (tid & 7) * 8;
  const size_t base = ib + (size_t)(oy0+sy)*WW + ox0 + sx0;
  float pn[8], rn[8];
  {
    float4 p0 = *(const float4*)&pold[base];
    float4 p1 = *(const float4*)&pold[base+4];
    float4 r0 = *(const float4*)&rold[base];
    float4 r1 = *(const float4*)&rold[base+4];
    float4 q0 = *(const float4*)&qold[base];
    float4 q1 = *(const float4*)&qold[base+4];
    float4 x0 = *(const float4*)&xk[base];
    float4 x1 = *(const float4*)&xk[base+4];
    float pv[8] = {p0.x,p0.y,p0.z,p0.w, p1.x,p1.y,p1.z,p1.w};
    float rv[8] = {r0.x,r0.y,r0.z,r0.w, r1.x,r1.y,r1.z,r1.w};
    float qv[8] = {q0.x,q0.y,q0.z,q0.w, q1.x,q1.y,q1.z,q1.w};
    float xv[8] = {x0.x,x0.y,x0.z,x0.w, x1.x,x1.y,x1.z,x1.w};
    #pragma unroll
    for (int k = 0; k < 8; k++) {
      rn[k] = fmaf(al, qv[k], rv[k]);
      pn[k] = fmaf(be, pv[k], -rn[k]);
      xv[k] = fmaf(al, pv[k], xv[k]);
      ssrc[sy+4][sx0+4+k] = pn[k];
    }
    *(float4*)&pnew[base]   = make_float4(pn[0], pn[1], pn[2], pn[3]);
    *(float4*)&pnew[base+4] = make_float4(pn[4], pn[5], pn[6], pn[7]);
    *(float4*)&rnew[base]   = make_float4(rn[0], rn[1], rn[2], rn[3]);
    *(float4*)&rnew[base+4] = make_float4(rn[4], rn[5], rn[6], rn[7]);
    *(float4*)&xk[base]     = make_float4(xv[0], xv[1], xv[2], xv[3]);
    *(float4*)&xk[base+4]   = make_float4(xv[4], xv[5], xv[6], xv[7]);
  }
  __syncthreads();

  float accv[8];
  apply_M2(ssrc, bandv, Gs, tab, tid, oy0, ox0, accv);

  float s_den = 0.f, s_rq = 0.f, s_qq = 0.f;
  #pragma unroll
  for (int k = 0; k < 8; k++) {
    float qv = accv[k];
    s_den += pn[k]*qv;
    s_rq  += rn[k]*qv;
    s_qq  += qv*qv;
  }
  if (storeQ) {
    *(float4*)&qnew[base]   = make_float4(accv[0], accv[1], accv[2], accv[3]);
    *(float4*)&qnew[base+4] = make_float4(accv[4], accv[5], accv[6], accv[7]);
  }
  reduce3_atomic(s_den, s_rq, s_qq, red, &scal[it*8+bimg], &scal[48+it*8+bimg],
                 &scal[96+it*8+bimg]);
}

__launch_bounds__(256)
__global__ void k_final(const float* __restrict__ xk, const float* __restrict__ p,
                        const float* __restrict__ num, const float* __restrict__ den,
                        float* __restrict__ out) {
  const int tid = threadIdx.x;
  const int bimg = blockIdx.x >> 8;
  const size_t idx4 = (size_t)blockIdx.x * 256 + tid;
  const float al = num[bimg] / den[bimg];
  float4 xv = ((const float4*)xk)[idx4];
  float4 pv = ((const float4*)p)[idx4];
  float4 o;
  o.x = xv.x + al*pv.x; o.y = xv.y + al*pv.y; o.z = xv.z + al*pv.z; o.w = xv.w + al*pv.w;
  ((float4*)out)[idx4] = o;
}

extern "C" void kernel_launch(void* const* d_in, const int* in_sizes, int n_in,
                              void* d_out, int out_size, void* d_ws, size_t ws_size,
                              hipStream_t stream) {
  const float* sino = (const float*)d_in[0];
  const float* x    = (const float*)d_in[1];
  const float* laam = (const float*)d_in[2];
  const float* miu  = (const float*)d_in[3];
  const float* Kw   = (const float*)d_in[4];
  const float* Ka   = (const float*)d_in[5];
  const float* W1   = (const float*)d_in[6];
  const float* b1   = (const float*)d_in[7];
  const float* W2   = (const float*)d_in[8];
  const float* b2   = (const float*)d_in[9];
  const float* W3   = (const float*)d_in[10];
  const float* b3   = (const float*)d_in[11];

  float* ws = (float*)d_ws;
  float* tail = ws + (size_t)6*NTOT;
  float* tab  = tail;                  // 2025 (pad 2048)
  float* scal = tail + 2048;           // 192: den[48] rq[48] qq[48] rtr[48]
  ushort* w2pk = (ushort*)(scal + 192);
  uint*   w1pk = (uint*)(w2pk + 9216);
  uint*   b1pk = w1pk + 144;
  ushort* w3fr = (ushort*)(b1pk + 16);
  float* dout = (float*)d_out;

  k_prep<<<1, 1024, 0, stream>>>(Ka, Kw, miu, W1, b1, W2, W3, tab, w2pk, w1pk,
                                 b1pk, w3fr, scal);

  float* xk = ws;
  k_cnn<<<dim3(32,32,8), 512, 0, stream>>>(x, w2pk, w1pk, b1pk, w3fr, b2, b3, xk);

  dim3 mg(8,16,8);
  float* rA = ws + (size_t)NTOT;
  float* rB = ws + 2*(size_t)NTOT;
  float* pA = ws + 3*(size_t)NTOT;
  float* pB = ws + 4*(size_t)NTOT;
  float* qB = ws + 5*(size_t)NTOT;
  float* qA = dout;
  k_M0<<<mg,256,0,stream>>>(xk, sino, x, rA, pA, tab, Ka, Kw, laam, miu, &scal[144]);
  k_M<1><<<mg,256,0,stream>>>(pA, nullptr, qA, nullptr, tab,
                              nullptr, nullptr, &scal[0], &scal[48], &scal[96]);
  float *rc=rA, *rn=rB, *pc=pA, *pn=pB, *qc=qA, *qn=qB;
  for (int it = 1; it <= 5; it++) {
    k_it<<<mg,256,0,stream>>>(xk, rc, rn, pc, pn, qc, qn, tab, scal,
                              it, it < 5 ? 1 : 0);
    float* t;
    t = rc; rc = rn; rn = t;
    t = pc; pc = pn; pn = t;
    t = qc; qc = qn; qn = t;
  }
  k_final<<<2048,256,0,stream>>>(xk, pc, &scal[144+40], &scal[40], dout);
}

// Round 16
// 360.153 us; speedup vs baseline: 1.1618x; 1.0085x over previous
//
#include <hip/hip_runtime.h>

#define HH 512
#define WW 512
#define BB 8
#define IMG (HH*WW)
#define NTOT (BB*IMG)

typedef float f32x4 __attribute__((ext_vector_type(4)));
typedef _Float16 half8 __attribute__((ext_vector_type(8)));

__device__ inline uint f2h2(float a, float b) {
  uint d; asm("v_cvt_pkrtz_f16_f32 %0, %1, %2" : "=v"(d) : "v"(a), "v"(b)); return d;
}
__device__ inline uint pkfma(uint a, uint b, uint c) {
  uint d; asm("v_pk_fma_f16 %0, %1, %2, %3" : "=v"(d) : "v"(a), "v"(b), "v"(c)); return d;
}
__device__ inline uint pkmax0(uint a) {
  uint d, z = 0u; asm("v_pk_max_f16 %0, %1, %2" : "=v"(d) : "v"(a), "v"(z)); return d;
}

__device__ inline void atomic_block_sum(float part, float* red, float* dst) {
  for (int off = 32; off > 0; off >>= 1) part += __shfl_down(part, off, 64);
  int lane = threadIdx.x & 63, w = threadIdx.x >> 6;
  if (lane == 0) red[w] = part;
  __syncthreads();
  if (threadIdx.x == 0) atomicAdd(dst, red[0] + red[1] + red[2] + red[3]);
}

__device__ inline void reduce3_atomic(float a, float b, float c, float* red,
                                      float* da, float* db, float* dc) {
  for (int off = 32; off > 0; off >>= 1) {
    a += __shfl_down(a, off, 64);
    b += __shfl_down(b, off, 64);
    c += __shfl_down(c, off, 64);
  }
  int lane = threadIdx.x & 63, w = threadIdx.x >> 6;
  if (lane == 0) { red[w*3] = a; red[w*3+1] = b; red[w*3+2] = c; }
  __syncthreads();
  if (threadIdx.x == 0) {
    atomicAdd(da, red[0]+red[3]+red[6]+red[9]);
    if (db) atomicAdd(db, red[1]+red[4]+red[7]+red[10]);
    if (dc) atomicAdd(dc, red[2]+red[5]+red[8]+red[11]);
  }
}

// masks for boundary-corrected stencils: t = 0(row0),1(row1),2(interior),3(H-2),4(H-1)
__device__ inline bool mA5(int t, int e) {
  return (t==0) ? (e<=2) : (t==1) ? (e<=3) : (t==3) ? (e>=1) : (t==4) ? (e>=2) : true;
}
__device__ inline bool mW3(int t, int e) {
  return (t==0) ? (e<=1) : (t==4) ? (e>=1) : true;
}

// ---------------- prep: scalars, 25x81 stencil table, fp16 weight packing ----------
__global__ void k_prep(const float* __restrict__ Ka, const float* __restrict__ Kw,
                       const float* __restrict__ miu,
                       const float* __restrict__ W1, const float* __restrict__ b1,
                       const float* __restrict__ W2, const float* __restrict__ W3,
                       float* __restrict__ tab, ushort* __restrict__ w2pk,
                       uint* __restrict__ w1pk, uint* __restrict__ b1pk,
                       ushort* __restrict__ w3fr, float* __restrict__ scal) {
  __shared__ float lka[25], lkw[36], lw1[288], lw3[288];
  int tid = threadIdx.x;   // 1024 threads
  if (tid < 192) scal[tid] = 0.f;
  if (tid < 25) lka[tid] = Ka[tid];
  if (tid < 36) lkw[tid] = Kw[tid];
  if (tid < 288) { lw1[tid] = W1[tid]; lw3[tid] = W3[tid]; }
  __syncthreads();
  const float mu = miu[0];
  #pragma unroll
  for (int k = 0; k < 2; k++) {
    int idx = tid + k*1024;
    if (idx < 2025) {
      int c = idx / 81, o = idx - c*81;
      int ty = c / 5, tx = c - 5*ty;
      int uy = o / 9 - 4, ux = o % 9 - 4;
      float s = 0.f;
      for (int ey = 0; ey < 5; ey++)
        for (int ex = 0; ex < 5; ex++) {
          int dy = ey + uy, dx = ex + ux;
          if (dy >= 0 && dy < 5 && dx >= 0 && dx < 5 && mA5(ty,ey) && mA5(tx,ex))
            s += lka[ey*5+ex] * lka[dy*5+dx];
        }
      float sw = 0.f;
      for (int ch = 0; ch < 4; ch++)
        for (int ey = 0; ey < 3; ey++)
          for (int ex = 0; ex < 3; ex++) {
            int dy = ey + uy, dx = ex + ux;
            if (dy >= 0 && dy < 3 && dx >= 0 && dx < 3 && mW3(ty,ey) && mW3(tx,ex))
              sw += lkw[ch*9+ey*3+ex] * lkw[ch*9+dy*3+dx];
          }
      tab[idx] = s + mu * sw;
    }
  }
  #pragma unroll
  for (int k = 0; k < 9; k++) {
    int i = tid + k*1024;
    int j = i & 7, l = (i >> 3) & 63, f = i >> 9;
    int t5 = f >> 1, h = f & 1;
    int co = 16*h + (l & 15), ci = 8*(l >> 4) + j;
    w2pk[i] = (ushort)(f2h2(W2[(co*32 + ci)*9 + t5], 0.f) & 0xffffu);
  }
  if (tid < 144) {
    int cp = tid / 9, t = tid % 9;
    w1pk[tid] = f2h2(lw1[(2*cp)*9 + t], lw1[(2*cp+1)*9 + t]);
  }
  if (tid < 16) b1pk[tid] = f2h2(b1[2*tid], b1[2*tid+1]);
  if (tid < 512) {
    int j = tid & 7, l = tid >> 3;
    int tap = l & 15, ch = 8*(l >> 4) + j;
    w3fr[tid] = (tap < 9) ? (ushort)(f2h2(lw3[ch*9 + tap], 0.f) & 0xffffu) : (ushort)0;
  }
}

// ---------------- fused CNN: xk = cnn(x), fp16/MFMA --------------------------------
// h1u px-group offsets XOR-swizzled by strip parity: off(px) = px*4 ^ ((px>>2&1)<<2)
// -> conv1 stores go from 4-way to 2-way bank conflicts (odd strips use odd groups).
__launch_bounds__(512, 2)
__global__ void k_cnn(const float* __restrict__ x,
                      const ushort* __restrict__ w2pk, const uint* __restrict__ w1pk,
                      const uint* __restrict__ b1pk, const ushort* __restrict__ w3fr,
                      const float* __restrict__ b2, const float* __restrict__ b3,
                      float* __restrict__ xk) {
  __shared__ __align__(16) uint  h1u[7040];         // 20 x 352
  __shared__ __align__(16) uint  h2u[5472];         // 18 x 304; head doubles as xs
  uint* xs_h2 = h2u;

  const int tid = threadIdx.x;
  const int bimg = blockIdx.z;
  const int oy0 = blockIdx.y * 16, ox0 = blockIdx.x * 16;
  const float* xim = x + (size_t)bimg * IMG;

  for (int i = tid; i < 528; i += 512) {
    int ly = i / 24, lx = i % 24;
    int gy = oy0 + ly - 3, gx = ox0 + lx - 4;
    float v = 0.f;
    if ((unsigned)gy < HH && (unsigned)gx < WW) v = xim[gy*WW + gx];
    xs_h2[i] = f2h2(v, v);
  }
  __syncthreads();

  // ---- conv1 ----
  {
    const int cp = tid & 15;
    const int sg = tid >> 4;
    uint w1r[9];
    #pragma unroll
    for (int k = 0; k < 9; k++) w1r[k] = w1pk[cp*9 + k];
    const uint b1v = b1pk[cp];
    const int kg = cp >> 2, cl = cp & 3;
    #pragma unroll 1
    for (int s = sg; s < 100; s += 32) {
      int row = s / 5, st = s - 5*row;
      int px0 = st * 4;
      uint acc0 = b1v, acc1 = b1v, acc2 = b1v, acc3 = b1v;
      #pragma unroll
      for (int ky = 0; ky < 3; ky++) {
        int base = (row + ky) * 24 + px0;
        uint4 xa = *(const uint4*)&xs_h2[base];
        uint4 xb = *(const uint4*)&xs_h2[base + 4];
        uint xu[8] = {xa.x, xa.y, xa.z, xa.w, xb.x, xb.y, xb.z, xb.w};
        #pragma unroll
        for (int kx = 0; kx < 3; kx++) {
          uint w = w1r[ky*3 + kx];
          acc0 = pkfma(w, xu[1 + kx], acc0);
          acc1 = pkfma(w, xu[2 + kx], acc1);
          acc2 = pkfma(w, xu[3 + kx], acc2);
          acc3 = pkfma(w, xu[4 + kx], acc3);
        }
      }
      int Y = oy0 + row - 2;
      bool rin = (unsigned)Y < HH;
      const int swz = (st & 1) << 2;
      int ob = row*352 + kg*88 + px0*4 + cl;
      #pragma unroll
      for (int i = 0; i < 4; i++) {
        int X = ox0 + px0 + i - 2;
        uint v = (rin && (unsigned)X < WW) ?
                 pkmax0(i == 0 ? acc0 : (i == 1 ? acc1 : (i == 2 ? acc2 : acc3))) : 0u;
        h1u[ob + (i*4 ^ swz)] = v;
      }
    }
  }
  __syncthreads();

  // ---- conv2 via MFMA f16 (reads apply the same px-group swizzle) ----
  const int wv = tid >> 6, lane = tid & 63;
  const int nn = lane & 15, kg = lane >> 4;
  {
    half8 afr[9][2];
    #pragma unroll
    for (int t5 = 0; t5 < 9; t5++) {
      afr[t5][0] = ((const half8*)w2pk)[(t5*2 + 0)*64 + lane];
      afr[t5][1] = ((const half8*)w2pk)[(t5*2 + 1)*64 + lane];
    }
    float b2A[4], b2B[4];
    #pragma unroll
    for (int j = 0; j < 4; j++) { b2A[j] = b2[4*kg + j]; b2B[j] = b2[16 + 4*kg + j]; }

    #pragma unroll 1
    for (int t = wv; t < 27; t += 8) {
      int rp = t / 3, cs = t - 3*rp;
      int tx0 = (cs == 2) ? 10 : (cs << 3);
      int brow = 2*rp + (nn >> 3);
      int bcol = tx0 + (nn & 7);
      f32x4 accA = {0.f,0.f,0.f,0.f}, accB = {0.f,0.f,0.f,0.f};
      #pragma unroll
      for (int ky = 0; ky < 3; ky++)
        #pragma unroll
        for (int kx = 0; kx < 3; kx++) {
          int px = bcol + kx;
          int poff = (px*4) ^ (((px >> 2) & 1) << 2);
          const half8 bfr = *(const half8*)&h1u[(brow+ky)*352 + kg*88 + poff];
          accA = __builtin_amdgcn_mfma_f32_16x16x32_f16(afr[ky*3+kx][0], bfr, accA, 0, 0, 0);
          accB = __builtin_amdgcn_mfma_f32_16x16x32_f16(afr[ky*3+kx][1], bfr, accB, 0, 0, 0);
        }
      int gy = oy0 + brow - 1, gx = ox0 + bcol - 1;
      bool inb = ((unsigned)gy < HH) && ((unsigned)gx < WW);
      float v0 = inb ? fmaxf(accA[0] + b2A[0], 0.f) : 0.f;
      float v1 = inb ? fmaxf(accA[1] + b2A[1], 0.f) : 0.f;
      float v2 = inb ? fmaxf(accA[2] + b2A[2], 0.f) : 0.f;
      float v3 = inb ? fmaxf(accA[3] + b2A[3], 0.f) : 0.f;
      uint2 uA = make_uint2(f2h2(v0, v1), f2h2(v2, v3));
      v0 = inb ? fmaxf(accB[0] + b2B[0], 0.f) : 0.f;
      v1 = inb ? fmaxf(accB[1] + b2B[1], 0.f) : 0.f;
      v2 = inb ? fmaxf(accB[2] + b2B[2], 0.f) : 0.f;
      v3 = inb ? fmaxf(accB[3] + b2B[3], 0.f) : 0.f;
      uint2 uB = make_uint2(f2h2(v0, v1), f2h2(v2, v3));
      int base = brow*304 + bcol*4 + (kg & 1)*2;
      *(uint2*)&h2u[base + (kg >> 1)*76]       = uA;
      *(uint2*)&h2u[base + (2 + (kg >> 1))*76] = uB;
    }
  }
  __syncthreads();

  // ---- conv3 stage 1 via MFMA (Tlds aliased onto dead h1u) ----
  float* Tlds = (float*)h1u;
  {
    const half8 w3f = ((const half8*)w3fr)[lane];
    const int tap = nn;
    #pragma unroll 1
    for (int t = wv; t < 27; t += 8) {
      int rp = t / 3, cs = t - 3*rp;
      int tx0 = (cs == 2) ? 10 : (cs << 3);
      int ay = 2*rp + (nn >> 3);
      int ax = tx0 + (nn & 7);
      const half8 afrag = *(const half8*)&h2u[ay*304 + kg*76 + ax*4];
      f32x4 z = {0.f,0.f,0.f,0.f};
      f32x4 T4 = __builtin_amdgcn_mfma_f32_16x16x32_f16(afrag, w3f, z, 0, 0, 0);
      if (tap < 9) {
        int ty = 2*rp + (kg >> 1);
        int txb = tx0 + 4*(kg & 1);
        float* dst = &Tlds[ty*180 + tap*20 + txb];
        if (cs == 2) {
          dst[0] = T4[0]; dst[1] = T4[1]; dst[2] = T4[2]; dst[3] = T4[3];
        } else {
          *(f32x4*)dst = T4;
        }
      }
    }
  }
  __syncthreads();

  // ---- conv3 gather + residual ----
  {
    const int half = tid & 1, px = tid >> 1;
    const int oy = px >> 4, ox = px & 15;
    float s = 0.f;
    if (half == 0) {
      #pragma unroll
      for (int t = 0; t < 4; t++)
        s += Tlds[(oy + t/3)*180 + t*20 + (ox + t%3)];
    } else {
      #pragma unroll
      for (int t = 4; t < 9; t++)
        s += Tlds[(oy + t/3)*180 + t*20 + (ox + t%3)];
    }
    float other = __shfl_xor(s, 1, 64);
    if (half == 0) {
      float tot = s + other + b3[0] + xim[(size_t)(oy0+oy)*WW + ox0 + ox];
      xk[(size_t)bimg*IMG + (size_t)(oy0+oy)*WW + ox0 + ox] = tot;
    }
  }
}

// ---------------- M-apply: G-stencil + table-corrected boundary band ---------------
__device__ __forceinline__ void apply_M2(const float (*ssrc)[76], float* bandv,
    const float* Gs, const float* __restrict__ tab,
    int tid, int oy0, int ox0, float* accv) {
  const int sy = tid >> 3, sx0 = (tid & 7) * 8;
  #pragma unroll
  for (int k = 0; k < 8; k++) accv[k] = 0.f;
  #pragma unroll 1
  for (int oyy = 0; oyy < 9; oyy++) {
    float g[9];
    #pragma unroll
    for (int t = 0; t < 9; t++) g[t] = Gs[oyy*9+t];
    const float* row = &ssrc[sy+oyy][sx0];
    float4 r0 = *(const float4*)(row);
    float4 r1 = *(const float4*)(row+4);
    float4 r2 = *(const float4*)(row+8);
    float4 r3 = *(const float4*)(row+12);
    float v[16] = {r0.x,r0.y,r0.z,r0.w, r1.x,r1.y,r1.z,r1.w,
                   r2.x,r2.y,r2.z,r2.w, r3.x,r3.y,r3.z,r3.w};
    #pragma unroll
    for (int k = 0; k < 8; k++) {
      float a = accv[k];
      #pragma unroll
      for (int t = 0; t < 9; t++) a = fmaf(g[t], v[k+t], a);
      accv[k] = a;
    }
  }
  const int by = blockIdx.y, bx = blockIdx.x;
  const bool eT = (by == 0), eB = (by == (int)gridDim.y - 1);
  const bool eL = (bx == 0), eR = (bx == (int)gridDim.x - 1);
  if (eT | eB | eL | eR) {
    const int nTop = eT ? 128 : 0;
    const int nBot = eB ? 128 : 0;
    const int yl = eT ? 2 : 0, yh = eB ? 30 : 32;
    const int nL = eL ? 2*(yh-yl) : 0;
    const int nR = eR ? 2*(yh-yl) : 0;
    const int nBand = nTop + nBot + nL + nR;
    if (tid < nBand) {
      int i = tid, bsy, bsx;
      if (i < nTop) { bsy = i >> 6; bsx = i & 63; }
      else if (i < nTop + nBot) { i -= nTop; bsy = 30 + (i >> 6); bsx = i & 63; }
      else if (i < nTop + nBot + nL) { i -= nTop + nBot; bsy = yl + (i >> 1); bsx = i & 1; }
      else { i -= nTop + nBot + nL; bsy = yl + (i >> 1); bsx = 62 + (i & 1); }
      const int gy = oy0 + bsy, gx = ox0 + bsx;
      int ty = (gy == 0) ? 0 : (gy == 1) ? 1 : (gy == HH-1) ? 4 : (gy == HH-2) ? 3 : 2;
      int tx = (gx == 0) ? 0 : (gx == 1) ? 1 : (gx == WW-1) ? 4 : (gx == WW-2) ? 3 : 2;
      const float* S = tab + (ty*5 + tx)*81;
      float a = 0.f;
      #pragma unroll
      for (int oy = 0; oy < 9; oy++) {
        const float* r = &ssrc[bsy+oy][bsx];
        #pragma unroll
        for (int ox = 0; ox < 9; ox++) a = fmaf(S[oy*9+ox], r[ox], a);
      }
      bandv[tid] = a;
    }
    __syncthreads();
    #pragma unroll
    for (int k = 0; k < 8; k++) {
      const int sx = sx0 + k;
      const int gy = oy0 + sy, gx = ox0 + sx;
      if ((gy < 2) || (gy >= HH-2) || (gx < 2) || (gx >= WW-2)) {
        int idx;
        if (eT && sy < 2) idx = sy*64 + sx;
        else if (eB && sy >= 30) idx = nTop + (sy-30)*64 + sx;
        else if (eL && sx < 2) idx = nTop + nBot + (sy-yl)*2 + sx;
        else idx = nTop + nBot + nL + (sy-yl)*2 + (sx-62);
        accv[k] = bandv[idx];
      }
    }
  }
}

// ---------------- k_M0: fused rhs + r = M(xk) - rhs, p = -r, rtr reduction ---------
__launch_bounds__(256)
__global__ void k_M0(const float* __restrict__ xk, const float* __restrict__ sino,
                     const float* __restrict__ x,
                     float* __restrict__ outR, float* __restrict__ outP,
                     const float* __restrict__ tab,
                     const float* __restrict__ Ka, const float* __restrict__ Kw,
                     const float* __restrict__ laam, const float* __restrict__ miu,
                     float* __restrict__ rtrOut) {
  __shared__ __align__(16) float ssrc[40][76];
  __shared__ __align__(16) float tbuf[36][68];
  __shared__ __align__(16) float ssin[36][68];
  __shared__ __align__(16) float sx[36][68];
  __shared__ float Gs[81], kas[25], kws[36];
  __shared__ float red[4];
  const int tid = threadIdx.x;
  const int bimg = blockIdx.z;
  const int oy0 = blockIdx.y*32, ox0 = blockIdx.x*64;
  if (tid < 81) Gs[tid] = tab[972 + tid];
  if (tid >= 81 && tid < 106) kas[tid-81] = Ka[tid-81];
  if (tid >= 106 && tid < 142) kws[tid-106] = Kw[tid-106];
  const float mu = miu[0];
  const float lam = laam[0];
  const float* sxk = xk + (size_t)bimg*IMG;
  const float* ssi = sino + (size_t)bimg*IMG;
  const float* sxi = x + (size_t)bimg*IMG;

  for (int i = tid; i < 40*76; i += 256) {
    int ly = i/76, lx = i%76;
    int gy = oy0 + ly - 4, gx = ox0 + lx - 4;
    bool in = (lx < 72) && (gy >= 0 && gy < HH && gx >= 0 && gx < WW);
    ssrc[ly][lx] = in ? sxk[gy*WW+gx] : 0.f;
  }
  for (int i = tid; i < 36*68; i += 256) {
    int ly = i/68, lx = i%68;
    int gy = oy0 + ly - 2, gx = ox0 + lx - 2;
    bool in = (gy >= 0 && gy < HH && gx >= 0 && gx < WW);
    ssin[ly][lx] = in ? ssi[gy*WW+gx] : 0.f;
    sx[ly][lx]   = in ? sxi[gy*WW+gx] : 0.f;
  }
  __syncthreads();

  float accv[8];
  apply_M2(ssrc, &tbuf[0][0], Gs, tab, tid, oy0, ox0, accv);

  const int sy = tid >> 3, sx0 = (tid & 7) * 8;
  float rhsv[8];
  #pragma unroll
  for (int k = 0; k < 8; k++) rhsv[k] = 0.f;
  {
    #pragma unroll
    for (int dy = 0; dy < 5; dy++) {
      const float* row = &ssin[sy+4-dy][sx0];
      float4 r0 = *(const float4*)(row);
      float4 r1 = *(const float4*)(row+4);
      float4 r2 = *(const float4*)(row+8);
      float w[12] = {r0.x,r0.y,r0.z,r0.w, r1.x,r1.y,r1.z,r1.w, r2.x,r2.y,r2.z,r2.w};
      #pragma unroll
      for (int k = 0; k < 8; k++)
        #pragma unroll
        for (int dx = 0; dx < 5; dx++)
          rhsv[k] = fmaf(kas[dy*5+dx], w[k+4-dx], rhsv[k]);
    }
  }
  #pragma unroll 1
  for (int ch = 0; ch < 4; ch++) {
    __syncthreads();
    {
      float kw[9];
      #pragma unroll
      for (int k = 0; k < 9; k++) kw[k] = kws[ch*9 + k];
      #pragma unroll 1
      for (int item = tid; item < 2244; item += 256) {
        int dy = item / 66, dx = item - 66*dy;
        int gy = oy0 + dy - 1, gx = ox0 + dx - 1;
        float v = 0.f;
        if (gy >= 0 && gy < HH && gx >= 0 && gx < WW) {
          float wu = 0.f;
          #pragma unroll
          for (int e = 0; e < 9; e++) wu = fmaf(kw[e], sx[dy + e/3][dx + e%3], wu);
          v = fmaxf(wu - lam, 0.f) - fmaxf(-wu - lam, 0.f);
        }
        tbuf[dy][dx] = v;
      }
    }
    __syncthreads();
    {
      float kw[9];
      #pragma unroll
      for (int k = 0; k < 9; k++) kw[k] = mu * kws[ch*9 + k];
      #pragma unroll
      for (int dy = 0; dy < 3; dy++) {
        const float* row = &tbuf[sy+2-dy][sx0];
        float4 r0 = *(const float4*)(row);
        float4 r1 = *(const float4*)(row+4);
        float4 r2 = *(const float4*)(row+8);
        float w[12] = {r0.x,r0.y,r0.z,r0.w, r1.x,r1.y,r1.z,r1.w, r2.x,r2.y,r2.z,r2.w};
        #pragma unroll
        for (int k = 0; k < 8; k++)
          #pragma unroll
          for (int dx = 0; dx < 3; dx++)
            rhsv[k] = fmaf(kw[dy*3+dx], w[k+2-dx], rhsv[k]);
      }
    }
  }

  const int gy = oy0 + sy, gx0 = ox0 + sx0;
  float part = 0.f;
  #pragma unroll
  for (int k = 0; k < 8; k++) {
    size_t idx = (size_t)bimg*IMG + gy*WW + gx0 + k;
    float rv = accv[k] - rhsv[k];
    outR[idx] = rv;
    outP[idx] = -rv;
    part += rv*rv;
  }
  atomic_block_sum(part, red, &rtrOut[bimg]);
}

// ---------------- k_M: MODE 1 (q0 + den/rq/qq) -------------------------------------
template<int MODE>
__launch_bounds__(256)
__global__ void k_M(const float* __restrict__ srcA, const float* __restrict__ srcB,
                    float* __restrict__ outQ, float* __restrict__ outP,
                    const float* __restrict__ tab,
                    const float* __restrict__ beN, const float* __restrict__ beD,
                    float* __restrict__ acc, float* __restrict__ rqOut,
                    float* __restrict__ qqOut) {
  __shared__ __align__(16) float ssrc[40][76];
  __shared__ float bandv[256];
  __shared__ float Gs[81];
  __shared__ float red[12];
  const int tid = threadIdx.x;
  const int bimg = blockIdx.z;
  const int oy0 = blockIdx.y*32, ox0 = blockIdx.x*64;
  if (tid < 81) Gs[tid] = tab[972 + tid];
  float be = 0.f;
  if (MODE == 2) be = beN[bimg] / beD[bimg];
  const float* sA = srcA + (size_t)bimg*IMG;
  const float* sB = (MODE == 2) ? srcB + (size_t)bimg*IMG : nullptr;

  for (int i = tid; i < 40*76; i += 256) {
    int ly = i/76, lx = i%76;
    int gy = oy0 + ly - 4, gx = ox0 + lx - 4;
    bool in = (lx < 72) && (gy >= 0 && gy < HH && gx >= 0 && gx < WW);
    float v = 0.f;
    if (MODE == 2) {
      if (in) {
        v = -sA[gy*WW+gx] + be * sB[gy*WW+gx];
        if (ly >= 4 && ly < 36 && lx >= 4 && lx < 68)
          outP[(size_t)bimg*IMG + gy*WW + gx] = v;
      }
    } else {
      if (in) v = sA[gy*WW+gx];
    }
    ssrc[ly][lx] = v;
  }
  __syncthreads();

  float accv[8];
  apply_M2(ssrc, bandv, Gs, tab, tid, oy0, ox0, accv);

  const int sy = tid >> 3, sx0 = (tid & 7) * 8;
  const int gy = oy0 + sy, gx0 = ox0 + sx0;
  if (MODE == 1) {
    float pq = 0.f, qq = 0.f;
    #pragma unroll
    for (int k = 0; k < 8; k++) {
      size_t idx = (size_t)bimg*IMG + gy*WW + gx0 + k;
      float pv = ssrc[sy+4][sx0+4+k];
      float qv = accv[k];
      outQ[idx] = qv;
      pq += pv * qv;
      qq += qv * qv;
    }
    reduce3_atomic(pq, -pq, qq, red, &acc[bimg], rqOut ? &rqOut[bimg] : nullptr,
                   qqOut ? &qqOut[bimg] : nullptr);
  } else {
    float part = 0.f;
    #pragma unroll
    for (int k = 0; k < 8; k++) {
      size_t idx = (size_t)bimg*IMG + gy*WW + gx0 + k;
      float pv = ssrc[sy+4][sx0+4+k];
      outQ[idx] = accv[k];
      part += pv * accv[k];
    }
    atomic_block_sum(part, red, &acc[bimg]);
  }
}

// ---------------- fused CG iteration: owner-interior in registers ------------------
__launch_bounds__(256)
__global__ void k_it(float* __restrict__ xk,
                     const float* __restrict__ rold, float* __restrict__ rnew,
                     const float* __restrict__ pold, float* __restrict__ pnew,
                     const float* __restrict__ qold, float* __restrict__ qnew,
                     const float* __restrict__ tab,
                     float* __restrict__ scal, int it, int storeQ) {
  __shared__ __align__(16) float ssrc[40][76];
  __shared__ float bandv[256];
  __shared__ float Gs[81];
  __shared__ float red[12];
  const int tid = threadIdx.x;
  const int bimg = blockIdx.z;
  const int oy0 = blockIdx.y*32, ox0 = blockIdx.x*64;
  if (tid < 81) Gs[tid] = tab[972 + tid];
  const float den_p = scal[       (it-1)*8 + bimg];
  const float rq_p  = scal[ 48 + (it-1)*8 + bimg];
  const float qq_p  = scal[ 96 + (it-1)*8 + bimg];
  const float rtr_p = scal[144 + (it-1)*8 + bimg];
  const float al = rtr_p / den_p;
  const float rtr_c = fmaf(al, fmaf(al, qq_p, 2.f*rq_p), rtr_p);
  const float be = rtr_c / rtr_p;
  if (tid == 0) scal[144 + it*8 + bimg] = rtr_c;
  const size_t ib = (size_t)bimg*IMG;

  // ---- halo frame (992 elems): p_new = be*p - (r + al*q), predicated ----
  for (int i = tid; i < 992; i += 256) {
    int ly, lx;
    if (i < 304) { ly = i/76; lx = i - 76*ly; }
    else if (i < 608) { int j = i-304; int q = j/76; ly = 36 + q; lx = j - 76*q; }
    else { int j = i-608; int q = j/12; ly = 4 + q; int c = j - 12*q; lx = (c < 4) ? c : c + 64; }
    int gy = oy0 + ly - 4, gx = ox0 + lx - 4;
    float v = 0.f;
    if (lx < 72 && (unsigned)gy < HH && (unsigned)gx < WW) {
      size_t g = ib + (size_t)gy*WW + gx;
      v = fmaf(be, pold[g], -fmaf(al, qold[g], rold[g]));
    }
    ssrc[ly][lx] = v;
  }

  // ---- interior by owners: coalesced float4, state kept in registers ----
  const int sy = tid >> 3, sx0 = (tid & 7) * 8;
  const size_t base = ib + (size_t)(oy0+sy)*WW + ox0 + sx0;
  float pn[8], rn[8];
  {
    float4 p0 = *(const float4*)&pold[base];
    float4 p1 = *(const float4*)&pold[base+4];
    float4 r0 = *(const float4*)&rold[base];
    float4 r1 = *(const float4*)&rold[base+4];
    float4 q0 = *(const float4*)&qold[base];
    float4 q1 = *(const float4*)&qold[base+4];
    float4 x0 = *(const float4*)&xk[base];
    float4 x1 = *(const float4*)&xk[base+4];
    float pv[8] = {p0.x,p0.y,p0.z,p0.w, p1.x,p1.y,p1.z,p1.w};
    float rv[8] = {r0.x,r0.y,r0.z,r0.w, r1.x,r1.y,r1.z,r1.w};
    float qv[8] = {q0.x,q0.y,q0.z,q0.w, q1.x,q1.y,q1.z,q1.w};
    float xv[8] = {x0.x,x0.y,x0.z,x0.w, x1.x,x1.y,x1.z,x1.w};
    #pragma unroll
    for (int k = 0; k < 8; k++) {
      rn[k] = fmaf(al, qv[k], rv[k]);
      pn[k] = fmaf(be, pv[k], -rn[k]);
      xv[k] = fmaf(al, pv[k], xv[k]);
      ssrc[sy+4][sx0+4+k] = pn[k];
    }
    *(float4*)&pnew[base]   = make_float4(pn[0], pn[1], pn[2], pn[3]);
    *(float4*)&pnew[base+4] = make_float4(pn[4], pn[5], pn[6], pn[7]);
    if (storeQ) {   // r_new unused after the last iteration
      *(float4*)&rnew[base]   = make_float4(rn[0], rn[1], rn[2], rn[3]);
      *(float4*)&rnew[base+4] = make_float4(rn[4], rn[5], rn[6], rn[7]);
    }
    *(float4*)&xk[base]     = make_float4(xv[0], xv[1], xv[2], xv[3]);
    *(float4*)&xk[base+4]   = make_float4(xv[4], xv[5], xv[6], xv[7]);
  }
  __syncthreads();

  float accv[8];
  apply_M2(ssrc, bandv, Gs, tab, tid, oy0, ox0, accv);

  float s_den = 0.f, s_rq = 0.f, s_qq = 0.f;
  #pragma unroll
  for (int k = 0; k < 8; k++) {
    float qv = accv[k];
    s_den += pn[k]*qv;
    s_rq  += rn[k]*qv;
    s_qq  += qv*qv;
  }
  if (storeQ) {
    *(float4*)&qnew[base]   = make_float4(accv[0], accv[1], accv[2], accv[3]);
    *(float4*)&qnew[base+4] = make_float4(accv[4], accv[5], accv[6], accv[7]);
  }
  reduce3_atomic(s_den, s_rq, s_qq, red, &scal[it*8+bimg], &scal[48+it*8+bimg],
                 &scal[96+it*8+bimg]);
}

__launch_bounds__(256)
__global__ void k_final(const float* __restrict__ xk, const float* __restrict__ p,
                        const float* __restrict__ num, const float* __restrict__ den,
                        float* __restrict__ out) {
  const int tid = threadIdx.x;
  const int bimg = blockIdx.x >> 8;
  const size_t idx4 = (size_t)blockIdx.x * 256 + tid;
  const float al = num[bimg] / den[bimg];
  float4 xv = ((const float4*)xk)[idx4];
  float4 pv = ((const float4*)p)[idx4];
  float4 o;
  o.x = xv.x + al*pv.x; o.y = xv.y + al*pv.y; o.z = xv.z + al*pv.z; o.w = xv.w + al*pv.w;
  ((float4*)out)[idx4] = o;
}

extern "C" void kernel_launch(void* const* d_in, const int* in_sizes, int n_in,
                              void* d_out, int out_size, void* d_ws, size_t ws_size,
                              hipStream_t stream) {
  const float* sino = (const float*)d_in[0];
  const float* x    = (const float*)d_in[1];
  const float* laam = (const float*)d_in[2];
  const float* miu  = (const float*)d_in[3];
  const float* Kw   = (const float*)d_in[4];
  const float* Ka   = (const float*)d_in[5];
  const float* W1   = (const float*)d_in[6];
  const float* b1   = (const float*)d_in[7];
  const float* W2   = (const float*)d_in[8];
  const float* b2   = (const float*)d_in[9];
  const float* W3   = (const float*)d_in[10];
  const float* b3   = (const float*)d_in[11];

  float* ws = (float*)d_ws;
  float* tail = ws + (size_t)6*NTOT;
  float* tab  = tail;                  // 2025 (pad 2048)
  float* scal = tail + 2048;           // 192: den[48] rq[48] qq[48] rtr[48]
  ushort* w2pk = (ushort*)(scal + 192);
  uint*   w1pk = (uint*)(w2pk + 9216);
  uint*   b1pk = w1pk + 144;
  ushort* w3fr = (ushort*)(b1pk + 16);
  float* dout = (float*)d_out;

  k_prep<<<1, 1024, 0, stream>>>(Ka, Kw, miu, W1, b1, W2, W3, tab, w2pk, w1pk,
                                 b1pk, w3fr, scal);

  float* xk = ws;
  k_cnn<<<dim3(32,32,8), 512, 0, stream>>>(x, w2pk, w1pk, b1pk, w3fr, b2, b3, xk);

  dim3 mg(8,16,8);
  float* rA = ws + (size_t)NTOT;
  float* rB = ws + 2*(size_t)NTOT;
  float* pA = ws + 3*(size_t)NTOT;
  float* pB = ws + 4*(size_t)NTOT;
  float* qB = ws + 5*(size_t)NTOT;
  float* qA = dout;
  k_M0<<<mg,256,0,stream>>>(xk, sino, x, rA, pA, tab, Ka, Kw, laam, miu, &scal[144]);
  k_M<1><<<mg,256,0,stream>>>(pA, nullptr, qA, nullptr, tab,
                              nullptr, nullptr, &scal[0], &scal[48], &scal[96]);
  float *rc=rA, *rn=rB, *pc=pA, *pn=pB, *qc=qA, *qn=qB;
  for (int it = 1; it <= 5; it++) {
    k_it<<<mg,256,0,stream>>>(xk, rc, rn, pc, pn, qc, qn, tab, scal,
                              it, it < 5 ? 1 : 0);
    float* t;
    t = rc; rc = rn; rn = t;
    t = pc; pc = pn; pn = t;
    t = qc; qc = qn; qn = t;
  }
  k_final<<<2048,256,0,stream>>>(xk, pc, &scal[144+40], &scal[40], dout);
}

// Round 17
// 356.912 us; speedup vs baseline: 1.1723x; 1.0091x over previous
//
#include <hip/hip_runtime.h>

#define HH 512
#define WW 512
#define BB 8
#define IMG (HH*WW)
#define NTOT (BB*IMG)

typedef float f32x4 __attribute__((ext_vector_type(4)));
typedef _Float16 half8 __attribute__((ext_vector_type(8)));

__device__ inline uint f2h2(float a, float b) {
  uint d; asm("v_cvt_pkrtz_f16_f32 %0, %1, %2" : "=v"(d) : "v"(a), "v"(b)); return d;
}
__device__ inline uint pkfma(uint a, uint b, uint c) {
  uint d; asm("v_pk_fma_f16 %0, %1, %2, %3" : "=v"(d) : "v"(a), "v"(b), "v"(c)); return d;
}
__device__ inline uint pkmax0(uint a) {
  uint d, z = 0u; asm("v_pk_max_f16 %0, %1, %2" : "=v"(d) : "v"(a), "v"(z)); return d;
}

__device__ inline void atomic_block_sum(float part, float* red, float* dst) {
  for (int off = 32; off > 0; off >>= 1) part += __shfl_down(part, off, 64);
  int lane = threadIdx.x & 63, w = threadIdx.x >> 6;
  if (lane == 0) red[w] = part;
  __syncthreads();
  if (threadIdx.x == 0) atomicAdd(dst, red[0] + red[1] + red[2] + red[3]);
}

__device__ inline void reduce3_atomic(float a, float b, float c, float* red,
                                      float* da, float* db, float* dc) {
  for (int off = 32; off > 0; off >>= 1) {
    a += __shfl_down(a, off, 64);
    b += __shfl_down(b, off, 64);
    c += __shfl_down(c, off, 64);
  }
  int lane = threadIdx.x & 63, w = threadIdx.x >> 6;
  if (lane == 0) { red[w*3] = a; red[w*3+1] = b; red[w*3+2] = c; }
  __syncthreads();
  if (threadIdx.x == 0) {
    atomicAdd(da, red[0]+red[3]+red[6]+red[9]);
    if (db) atomicAdd(db, red[1]+red[4]+red[7]+red[10]);
    if (dc) atomicAdd(dc, red[2]+red[5]+red[8]+red[11]);
  }
}

// masks for boundary-corrected stencils: t = 0(row0),1(row1),2(interior),3(H-2),4(H-1)
__device__ inline bool mA5(int t, int e) {
  return (t==0) ? (e<=2) : (t==1) ? (e<=3) : (t==3) ? (e>=1) : (t==4) ? (e>=2) : true;
}
__device__ inline bool mW3(int t, int e) {
  return (t==0) ? (e<=1) : (t==4) ? (e>=1) : true;
}

// ---------------- prep: scalars, 25x81 stencil table, fp16 weight packing ----------
__global__ void k_prep(const float* __restrict__ Ka, const float* __restrict__ Kw,
                       const float* __restrict__ miu,
                       const float* __restrict__ W1, const float* __restrict__ b1,
                       const float* __restrict__ W2, const float* __restrict__ W3,
                       float* __restrict__ tab, ushort* __restrict__ w2pk,
                       uint* __restrict__ w1pk, uint* __restrict__ b1pk,
                       ushort* __restrict__ w3fr, float* __restrict__ scal) {
  __shared__ float lka[25], lkw[36], lw1[288], lw3[288];
  int tid = threadIdx.x;   // 1024 threads
  if (tid < 192) scal[tid] = 0.f;
  if (tid < 25) lka[tid] = Ka[tid];
  if (tid < 36) lkw[tid] = Kw[tid];
  if (tid < 288) { lw1[tid] = W1[tid]; lw3[tid] = W3[tid]; }
  __syncthreads();
  const float mu = miu[0];
  #pragma unroll
  for (int k = 0; k < 2; k++) {
    int idx = tid + k*1024;
    if (idx < 2025) {
      int c = idx / 81, o = idx - c*81;
      int ty = c / 5, tx = c - 5*ty;
      int uy = o / 9 - 4, ux = o % 9 - 4;
      float s = 0.f;
      for (int ey = 0; ey < 5; ey++)
        for (int ex = 0; ex < 5; ex++) {
          int dy = ey + uy, dx = ex + ux;
          if (dy >= 0 && dy < 5 && dx >= 0 && dx < 5 && mA5(ty,ey) && mA5(tx,ex))
            s += lka[ey*5+ex] * lka[dy*5+dx];
        }
      float sw = 0.f;
      for (int ch = 0; ch < 4; ch++)
        for (int ey = 0; ey < 3; ey++)
          for (int ex = 0; ex < 3; ex++) {
            int dy = ey + uy, dx = ex + ux;
            if (dy >= 0 && dy < 3 && dx >= 0 && dx < 3 && mW3(ty,ey) && mW3(tx,ex))
              sw += lkw[ch*9+ey*3+ex] * lkw[ch*9+dy*3+dx];
          }
      tab[idx] = s + mu * sw;
    }
  }
  #pragma unroll
  for (int k = 0; k < 9; k++) {
    int i = tid + k*1024;
    int j = i & 7, l = (i >> 3) & 63, f = i >> 9;
    int t5 = f >> 1, h = f & 1;
    int co = 16*h + (l & 15), ci = 8*(l >> 4) + j;
    w2pk[i] = (ushort)(f2h2(W2[(co*32 + ci)*9 + t5], 0.f) & 0xffffu);
  }
  if (tid < 144) {
    int cp = tid / 9, t = tid % 9;
    w1pk[tid] = f2h2(lw1[(2*cp)*9 + t], lw1[(2*cp+1)*9 + t]);
  }
  if (tid < 16) b1pk[tid] = f2h2(b1[2*tid], b1[2*tid+1]);
  if (tid < 512) {
    int j = tid & 7, l = tid >> 3;
    int tap = l & 15, ch = 8*(l >> 4) + j;
    w3fr[tid] = (tap < 9) ? (ushort)(f2h2(lw3[ch*9 + tap], 0.f) & 0xffffu) : (ushort)0;
  }
}

// ---------------- fused CNN: xk = cnn(x), fp16/MFMA --------------------------------
__launch_bounds__(512, 2)
__global__ void k_cnn(const float* __restrict__ x,
                      const ushort* __restrict__ w2pk, const uint* __restrict__ w1pk,
                      const uint* __restrict__ b1pk, const ushort* __restrict__ w3fr,
                      const float* __restrict__ b2, const float* __restrict__ b3,
                      float* __restrict__ xk) {
  __shared__ __align__(16) uint  h1u[7040];         // 20 x 352
  __shared__ __align__(16) uint  h2u[5472];         // 18 x 304; head doubles as xs
  uint* xs_h2 = h2u;

  const int tid = threadIdx.x;
  const int bimg = blockIdx.z;
  const int oy0 = blockIdx.y * 16, ox0 = blockIdx.x * 16;
  const float* xim = x + (size_t)bimg * IMG;

  for (int i = tid; i < 528; i += 512) {
    int ly = i / 24, lx = i % 24;
    int gy = oy0 + ly - 3, gx = ox0 + lx - 4;
    float v = 0.f;
    if ((unsigned)gy < HH && (unsigned)gx < WW) v = xim[gy*WW + gx];
    xs_h2[i] = f2h2(v, v);
  }
  __syncthreads();

  // ---- conv1 ----
  {
    const int cp = tid & 15;
    const int sg = tid >> 4;
    uint w1r[9];
    #pragma unroll
    for (int k = 0; k < 9; k++) w1r[k] = w1pk[cp*9 + k];
    const uint b1v = b1pk[cp];
    const int kg = cp >> 2, cl = cp & 3;
    #pragma unroll 1
    for (int s = sg; s < 100; s += 32) {
      int row = s / 5, st = s - 5*row;
      int px0 = st * 4;
      uint acc0 = b1v, acc1 = b1v, acc2 = b1v, acc3 = b1v;
      #pragma unroll
      for (int ky = 0; ky < 3; ky++) {
        int base = (row + ky) * 24 + px0;
        uint4 xa = *(const uint4*)&xs_h2[base];
        uint4 xb = *(const uint4*)&xs_h2[base + 4];
        uint xu[8] = {xa.x, xa.y, xa.z, xa.w, xb.x, xb.y, xb.z, xb.w};
        #pragma unroll
        for (int kx = 0; kx < 3; kx++) {
          uint w = w1r[ky*3 + kx];
          acc0 = pkfma(w, xu[1 + kx], acc0);
          acc1 = pkfma(w, xu[2 + kx], acc1);
          acc2 = pkfma(w, xu[3 + kx], acc2);
          acc3 = pkfma(w, xu[4 + kx], acc3);
        }
      }
      int Y = oy0 + row - 2;
      bool rin = (unsigned)Y < HH;
      int ob = row*352 + kg*88 + px0*4 + cl;
      #pragma unroll
      for (int i = 0; i < 4; i++) {
        int X = ox0 + px0 + i - 2;
        uint v = (rin && (unsigned)X < WW) ?
                 pkmax0(i == 0 ? acc0 : (i == 1 ? acc1 : (i == 2 ? acc2 : acc3))) : 0u;
        h1u[ob + i*4] = v;
      }
    }
  }
  __syncthreads();

  // ---- conv2 via MFMA f16 ----
  const int wv = tid >> 6, lane = tid & 63;
  const int nn = lane & 15, kg = lane >> 4;
  {
    half8 afr[9][2];
    #pragma unroll
    for (int t5 = 0; t5 < 9; t5++) {
      afr[t5][0] = ((const half8*)w2pk)[(t5*2 + 0)*64 + lane];
      afr[t5][1] = ((const half8*)w2pk)[(t5*2 + 1)*64 + lane];
    }
    float b2A[4], b2B[4];
    #pragma unroll
    for (int j = 0; j < 4; j++) { b2A[j] = b2[4*kg + j]; b2B[j] = b2[16 + 4*kg + j]; }

    #pragma unroll 1
    for (int t = wv; t < 27; t += 8) {
      int rp = t / 3, cs = t - 3*rp;
      int tx0 = (cs == 2) ? 10 : (cs << 3);
      int brow = 2*rp + (nn >> 3);
      int bcol = tx0 + (nn & 7);
      f32x4 accA = {0.f,0.f,0.f,0.f}, accB = {0.f,0.f,0.f,0.f};
      #pragma unroll
      for (int ky = 0; ky < 3; ky++)
        #pragma unroll
        for (int kx = 0; kx < 3; kx++) {
          const half8 bfr = *(const half8*)&h1u[(brow+ky)*352 + kg*88 + (bcol+kx)*4];
          accA = __builtin_amdgcn_mfma_f32_16x16x32_f16(afr[ky*3+kx][0], bfr, accA, 0, 0, 0);
          accB = __builtin_amdgcn_mfma_f32_16x16x32_f16(afr[ky*3+kx][1], bfr, accB, 0, 0, 0);
        }
      int gy = oy0 + brow - 1, gx = ox0 + bcol - 1;
      bool inb = ((unsigned)gy < HH) && ((unsigned)gx < WW);
      float v0 = inb ? fmaxf(accA[0] + b2A[0], 0.f) : 0.f;
      float v1 = inb ? fmaxf(accA[1] + b2A[1], 0.f) : 0.f;
      float v2 = inb ? fmaxf(accA[2] + b2A[2], 0.f) : 0.f;
      float v3 = inb ? fmaxf(accA[3] + b2A[3], 0.f) : 0.f;
      uint2 uA = make_uint2(f2h2(v0, v1), f2h2(v2, v3));
      v0 = inb ? fmaxf(accB[0] + b2B[0], 0.f) : 0.f;
      v1 = inb ? fmaxf(accB[1] + b2B[1], 0.f) : 0.f;
      v2 = inb ? fmaxf(accB[2] + b2B[2], 0.f) : 0.f;
      v3 = inb ? fmaxf(accB[3] + b2B[3], 0.f) : 0.f;
      uint2 uB = make_uint2(f2h2(v0, v1), f2h2(v2, v3));
      int base = brow*304 + bcol*4 + (kg & 1)*2;
      *(uint2*)&h2u[base + (kg >> 1)*76]       = uA;
      *(uint2*)&h2u[base + (2 + (kg >> 1))*76] = uB;
    }
  }
  __syncthreads();

  // ---- conv3 stage 1 via MFMA (Tlds aliased onto dead h1u) ----
  float* Tlds = (float*)h1u;
  {
    const half8 w3f = ((const half8*)w3fr)[lane];
    const int tap = nn;
    #pragma unroll 1
    for (int t = wv; t < 27; t += 8) {
      int rp = t / 3, cs = t - 3*rp;
      int tx0 = (cs == 2) ? 10 : (cs << 3);
      int ay = 2*rp + (nn >> 3);
      int ax = tx0 + (nn & 7);
      const half8 afrag = *(const half8*)&h2u[ay*304 + kg*76 + ax*4];
      f32x4 z = {0.f,0.f,0.f,0.f};
      f32x4 T4 = __builtin_amdgcn_mfma_f32_16x16x32_f16(afrag, w3f, z, 0, 0, 0);
      if (tap < 9) {
        int ty = 2*rp + (kg >> 1);
        int txb = tx0 + 4*(kg & 1);
        float* dst = &Tlds[ty*180 + tap*20 + txb];
        if (cs == 2) {
          dst[0] = T4[0]; dst[1] = T4[1]; dst[2] = T4[2]; dst[3] = T4[3];
        } else {
          *(f32x4*)dst = T4;
        }
      }
    }
  }
  __syncthreads();

  // ---- conv3 gather + residual ----
  {
    const int half = tid & 1, px = tid >> 1;
    const int oy = px >> 4, ox = px & 15;
    float s = 0.f;
    if (half == 0) {
      #pragma unroll
      for (int t = 0; t < 4; t++)
        s += Tlds[(oy + t/3)*180 + t*20 + (ox + t%3)];
    } else {
      #pragma unroll
      for (int t = 4; t < 9; t++)
        s += Tlds[(oy + t/3)*180 + t*20 + (ox + t%3)];
    }
    float other = __shfl_xor(s, 1, 64);
    if (half == 0) {
      float tot = s + other + b3[0] + xim[(size_t)(oy0+oy)*WW + ox0 + ox];
      xk[(size_t)bimg*IMG + (size_t)(oy0+oy)*WW + ox0 + ox] = tot;
    }
  }
}

// ---------------- M-apply: G-stencil + table-corrected boundary band ---------------
__device__ __forceinline__ void apply_M2(const float (*ssrc)[76], float* bandv,
    const float* Gs, const float* __restrict__ tab,
    int tid, int oy0, int ox0, float* accv) {
  const int sy = tid >> 3, sx0 = (tid & 7) * 8;
  #pragma unroll
  for (int k = 0; k < 8; k++) accv[k] = 0.f;
  #pragma unroll 1
  for (int oyy = 0; oyy < 9; oyy++) {
    float g[9];
    #pragma unroll
    for (int t = 0; t < 9; t++) g[t] = Gs[oyy*9+t];
    const float* row = &ssrc[sy+oyy][sx0];
    float4 r0 = *(const float4*)(row);
    float4 r1 = *(const float4*)(row+4);
    float4 r2 = *(const float4*)(row+8);
    float4 r3 = *(const float4*)(row+12);
    float v[16] = {r0.x,r0.y,r0.z,r0.w, r1.x,r1.y,r1.z,r1.w,
                   r2.x,r2.y,r2.z,r2.w, r3.x,r3.y,r3.z,r3.w};
    #pragma unroll
    for (int k = 0; k < 8; k++) {
      float a = accv[k];
      #pragma unroll
      for (int t = 0; t < 9; t++) a = fmaf(g[t], v[k+t], a);
      accv[k] = a;
    }
  }
  const int by = blockIdx.y, bx = blockIdx.x;
  const bool eT = (by == 0), eB = (by == (int)gridDim.y - 1);
  const bool eL = (bx == 0), eR = (bx == (int)gridDim.x - 1);
  if (eT | eB | eL | eR) {
    const int nTop = eT ? 128 : 0;
    const int nBot = eB ? 128 : 0;
    const int yl = eT ? 2 : 0, yh = eB ? 30 : 32;
    const int nL = eL ? 2*(yh-yl) : 0;
    const int nR = eR ? 2*(yh-yl) : 0;
    const int nBand = nTop + nBot + nL + nR;
    if (tid < nBand) {
      int i = tid, bsy, bsx;
      if (i < nTop) { bsy = i >> 6; bsx = i & 63; }
      else if (i < nTop + nBot) { i -= nTop; bsy = 30 + (i >> 6); bsx = i & 63; }
      else if (i < nTop + nBot + nL) { i -= nTop + nBot; bsy = yl + (i >> 1); bsx = i & 1; }
      else { i -= nTop + nBot + nL; bsy = yl + (i >> 1); bsx = 62 + (i & 1); }
      const int gy = oy0 + bsy, gx = ox0 + bsx;
      int ty = (gy == 0) ? 0 : (gy == 1) ? 1 : (gy == HH-1) ? 4 : (gy == HH-2) ? 3 : 2;
      int tx = (gx == 0) ? 0 : (gx == 1) ? 1 : (gx == WW-1) ? 4 : (gx == WW-2) ? 3 : 2;
      const float* S = tab + (ty*5 + tx)*81;
      float a = 0.f;
      #pragma unroll
      for (int oy = 0; oy < 9; oy++) {
        const float* r = &ssrc[bsy+oy][bsx];
        #pragma unroll
        for (int ox = 0; ox < 9; ox++) a = fmaf(S[oy*9+ox], r[ox], a);
      }
      bandv[tid] = a;
    }
    __syncthreads();
    #pragma unroll
    for (int k = 0; k < 8; k++) {
      const int sx = sx0 + k;
      const int gy = oy0 + sy, gx = ox0 + sx;
      if ((gy < 2) || (gy >= HH-2) || (gx < 2) || (gx >= WW-2)) {
        int idx;
        if (eT && sy < 2) idx = sy*64 + sx;
        else if (eB && sy >= 30) idx = nTop + (sy-30)*64 + sx;
        else if (eL && sx < 2) idx = nTop + nBot + (sy-yl)*2 + sx;
        else idx = nTop + nBot + nL + (sy-yl)*2 + (sx-62);
        accv[k] = bandv[idx];
      }
    }
  }
}

// ---------------- k_M0: fused rhs + r = M(xk) - rhs, p = -r, rtr reduction ---------
__launch_bounds__(256)
__global__ void k_M0(const float* __restrict__ xk, const float* __restrict__ sino,
                     const float* __restrict__ x,
                     float* __restrict__ outR, float* __restrict__ outP,
                     const float* __restrict__ tab,
                     const float* __restrict__ Ka, const float* __restrict__ Kw,
                     const float* __restrict__ laam, const float* __restrict__ miu,
                     float* __restrict__ rtrOut) {
  __shared__ __align__(16) float ssrc[40][76];
  __shared__ __align__(16) float tbuf[36][68];
  __shared__ __align__(16) float ssin[36][68];
  __shared__ __align__(16) float sx[36][68];
  __shared__ float Gs[81], kas[25], kws[36];
  __shared__ float red[4];
  const int tid = threadIdx.x;
  const int bimg = blockIdx.z;
  const int oy0 = blockIdx.y*32, ox0 = blockIdx.x*64;
  if (tid < 81) Gs[tid] = tab[972 + tid];
  if (tid >= 81 && tid < 106) kas[tid-81] = Ka[tid-81];
  if (tid >= 106 && tid < 142) kws[tid-106] = Kw[tid-106];
  const float mu = miu[0];
  const float lam = laam[0];
  const float* sxk = xk + (size_t)bimg*IMG;
  const float* ssi = sino + (size_t)bimg*IMG;
  const float* sxi = x + (size_t)bimg*IMG;

  for (int i = tid; i < 40*76; i += 256) {
    int ly = i/76, lx = i%76;
    int gy = oy0 + ly - 4, gx = ox0 + lx - 4;
    bool in = (lx < 72) && (gy >= 0 && gy < HH && gx >= 0 && gx < WW);
    ssrc[ly][lx] = in ? sxk[gy*WW+gx] : 0.f;
  }
  for (int i = tid; i < 36*68; i += 256) {
    int ly = i/68, lx = i%68;
    int gy = oy0 + ly - 2, gx = ox0 + lx - 2;
    bool in = (gy >= 0 && gy < HH && gx >= 0 && gx < WW);
    ssin[ly][lx] = in ? ssi[gy*WW+gx] : 0.f;
    sx[ly][lx]   = in ? sxi[gy*WW+gx] : 0.f;
  }
  __syncthreads();

  float accv[8];
  apply_M2(ssrc, &tbuf[0][0], Gs, tab, tid, oy0, ox0, accv);

  const int sy = tid >> 3, sx0 = (tid & 7) * 8;
  float rhsv[8];
  #pragma unroll
  for (int k = 0; k < 8; k++) rhsv[k] = 0.f;
  {
    #pragma unroll
    for (int dy = 0; dy < 5; dy++) {
      const float* row = &ssin[sy+4-dy][sx0];
      float4 r0 = *(const float4*)(row);
      float4 r1 = *(const float4*)(row+4);
      float4 r2 = *(const float4*)(row+8);
      float w[12] = {r0.x,r0.y,r0.z,r0.w, r1.x,r1.y,r1.z,r1.w, r2.x,r2.y,r2.z,r2.w};
      #pragma unroll
      for (int k = 0; k < 8; k++)
        #pragma unroll
        for (int dx = 0; dx < 5; dx++)
          rhsv[k] = fmaf(kas[dy*5+dx], w[k+4-dx], rhsv[k]);
    }
  }
  #pragma unroll 1
  for (int ch = 0; ch < 4; ch++) {
    __syncthreads();
    {
      float kw[9];
      #pragma unroll
      for (int k = 0; k < 9; k++) kw[k] = kws[ch*9 + k];
      #pragma unroll 1
      for (int item = tid; item < 2244; item += 256) {
        int dy = item / 66, dx = item - 66*dy;
        int gy = oy0 + dy - 1, gx = ox0 + dx - 1;
        float v = 0.f;
        if (gy >= 0 && gy < HH && gx >= 0 && gx < WW) {
          float wu = 0.f;
          #pragma unroll
          for (int e = 0; e < 9; e++) wu = fmaf(kw[e], sx[dy + e/3][dx + e%3], wu);
          v = fmaxf(wu - lam, 0.f) - fmaxf(-wu - lam, 0.f);
        }
        tbuf[dy][dx] = v;
      }
    }
    __syncthreads();
    {
      float kw[9];
      #pragma unroll
      for (int k = 0; k < 9; k++) kw[k] = mu * kws[ch*9 + k];
      #pragma unroll
      for (int dy = 0; dy < 3; dy++) {
        const float* row = &tbuf[sy+2-dy][sx0];
        float4 r0 = *(const float4*)(row);
        float4 r1 = *(const float4*)(row+4);
        float4 r2 = *(const float4*)(row+8);
        float w[12] = {r0.x,r0.y,r0.z,r0.w, r1.x,r1.y,r1.z,r1.w, r2.x,r2.y,r2.z,r2.w};
        #pragma unroll
        for (int k = 0; k < 8; k++)
          #pragma unroll
          for (int dx = 0; dx < 3; dx++)
            rhsv[k] = fmaf(kw[dy*3+dx], w[k+2-dx], rhsv[k]);
      }
    }
  }

  const int gy = oy0 + sy, gx0 = ox0 + sx0;
  float part = 0.f;
  #pragma unroll
  for (int k = 0; k < 8; k++) {
    size_t idx = (size_t)bimg*IMG + gy*WW + gx0 + k;
    float rv = accv[k] - rhsv[k];
    outR[idx] = rv;
    outP[idx] = -rv;
    part += rv*rv;
  }
  atomic_block_sum(part, red, &rtrOut[bimg]);
}

// ---------------- k_M: MODE 1 (q0 + den/rq/qq) -------------------------------------
template<int MODE>
__launch_bounds__(256)
__global__ void k_M(const float* __restrict__ srcA, const float* __restrict__ srcB,
                    float* __restrict__ outQ, float* __restrict__ outP,
                    const float* __restrict__ tab,
                    const float* __restrict__ beN, const float* __restrict__ beD,
                    float* __restrict__ acc, float* __restrict__ rqOut,
                    float* __restrict__ qqOut) {
  __shared__ __align__(16) float ssrc[40][76];
  __shared__ float bandv[256];
  __shared__ float Gs[81];
  __shared__ float red[12];
  const int tid = threadIdx.x;
  const int bimg = blockIdx.z;
  const int oy0 = blockIdx.y*32, ox0 = blockIdx.x*64;
  if (tid < 81) Gs[tid] = tab[972 + tid];
  float be = 0.f;
  if (MODE == 2) be = beN[bimg] / beD[bimg];
  const float* sA = srcA + (size_t)bimg*IMG;
  const float* sB = (MODE == 2) ? srcB + (size_t)bimg*IMG : nullptr;

  for (int i = tid; i < 40*76; i += 256) {
    int ly = i/76, lx = i%76;
    int gy = oy0 + ly - 4, gx = ox0 + lx - 4;
    bool in = (lx < 72) && (gy >= 0 && gy < HH && gx >= 0 && gx < WW);
    float v = 0.f;
    if (MODE == 2) {
      if (in) {
        v = -sA[gy*WW+gx] + be * sB[gy*WW+gx];
        if (ly >= 4 && ly < 36 && lx >= 4 && lx < 68)
          outP[(size_t)bimg*IMG + gy*WW + gx] = v;
      }
    } else {
      if (in) v = sA[gy*WW+gx];
    }
    ssrc[ly][lx] = v;
  }
  __syncthreads();

  float accv[8];
  apply_M2(ssrc, bandv, Gs, tab, tid, oy0, ox0, accv);

  const int sy = tid >> 3, sx0 = (tid & 7) * 8;
  const int gy = oy0 + sy, gx0 = ox0 + sx0;
  if (MODE == 1) {
    float pq = 0.f, qq = 0.f;
    #pragma unroll
    for (int k = 0; k < 8; k++) {
      size_t idx = (size_t)bimg*IMG + gy*WW + gx0 + k;
      float pv = ssrc[sy+4][sx0+4+k];
      float qv = accv[k];
      outQ[idx] = qv;
      pq += pv * qv;
      qq += qv * qv;
    }
    reduce3_atomic(pq, -pq, qq, red, &acc[bimg], rqOut ? &rqOut[bimg] : nullptr,
                   qqOut ? &qqOut[bimg] : nullptr);
  } else {
    float part = 0.f;
    #pragma unroll
    for (int k = 0; k < 8; k++) {
      size_t idx = (size_t)bimg*IMG + gy*WW + gx0 + k;
      float pv = ssrc[sy+4][sx0+4+k];
      outQ[idx] = accv[k];
      part += pv * accv[k];
    }
    atomic_block_sum(part, red, &acc[bimg]);
  }
}

// ---------------- fused CG iteration: owner-interior in registers ------------------
__launch_bounds__(256)
__global__ void k_it(float* __restrict__ xk,
                     const float* __restrict__ rold, float* __restrict__ rnew,
                     const float* __restrict__ pold, float* __restrict__ pnew,
                     const float* __restrict__ qold, float* __restrict__ qnew,
                     const float* __restrict__ tab,
                     float* __restrict__ scal, int it, int storeQ) {
  __shared__ __align__(16) float ssrc[40][76];
  __shared__ float bandv[256];
  __shared__ float Gs[81];
  __shared__ float red[12];
  const int tid = threadIdx.x;
  const int bimg = blockIdx.z;
  const int oy0 = blockIdx.y*32, ox0 = blockIdx.x*64;
  if (tid < 81) Gs[tid] = tab[972 + tid];
  const float den_p = scal[       (it-1)*8 + bimg];
  const float rq_p  = scal[ 48 + (it-1)*8 + bimg];
  const float qq_p  = scal[ 96 + (it-1)*8 + bimg];
  const float rtr_p = scal[144 + (it-1)*8 + bimg];
  const float al = rtr_p / den_p;
  const float rtr_c = fmaf(al, fmaf(al, qq_p, 2.f*rq_p), rtr_p);
  const float be = rtr_c / rtr_p;
  if (tid == 0) scal[144 + it*8 + bimg] = rtr_c;
  const size_t ib = (size_t)bimg*IMG;

  // ---- halo frame (992 elems): p_new = be*p - (r + al*q), predicated ----
  for (int i = tid; i < 992; i += 256) {
    int ly, lx;
    if (i < 304) { ly = i/76; lx = i - 76*ly; }
    else if (i < 608) { int j = i-304; int q = j/76; ly = 36 + q; lx = j - 76*q; }
    else { int j = i-608; int q = j/12; ly = 4 + q; int c = j - 12*q; lx = (c < 4) ? c : c + 64; }
    int gy = oy0 + ly - 4, gx = ox0 + lx - 4;
    float v = 0.f;
    if (lx < 72 && (unsigned)gy < HH && (unsigned)gx < WW) {
      size_t g = ib + (size_t)gy*WW + gx;
      v = fmaf(be, pold[g], -fmaf(al, qold[g], rold[g]));
    }
    ssrc[ly][lx] = v;
  }

  // ---- interior by owners: coalesced float4, state kept in registers ----
  const int sy = tid >> 3, sx0 = (tid & 7) * 8;
  const size_t base = ib + (size_t)(oy0+sy)*WW + ox0 + sx0;
  float pn[8], rn[8];
  {
    float4 p0 = *(const float4*)&pold[base];
    float4 p1 = *(const float4*)&pold[base+4];
    float4 r0 = *(const float4*)&rold[base];
    float4 r1 = *(const float4*)&rold[base+4];
    float4 q0 = *(const float4*)&qold[base];
    float4 q1 = *(const float4*)&qold[base+4];
    float4 x0 = *(const float4*)&xk[base];
    float4 x1 = *(const float4*)&xk[base+4];
    float pv[8] = {p0.x,p0.y,p0.z,p0.w, p1.x,p1.y,p1.z,p1.w};
    float rv[8] = {r0.x,r0.y,r0.z,r0.w, r1.x,r1.y,r1.z,r1.w};
    float qv[8] = {q0.x,q0.y,q0.z,q0.w, q1.x,q1.y,q1.z,q1.w};
    float xv[8] = {x0.x,x0.y,x0.z,x0.w, x1.x,x1.y,x1.z,x1.w};
    #pragma unroll
    for (int k = 0; k < 8; k++) {
      rn[k] = fmaf(al, qv[k], rv[k]);
      pn[k] = fmaf(be, pv[k], -rn[k]);
      xv[k] = fmaf(al, pv[k], xv[k]);
      ssrc[sy+4][sx0+4+k] = pn[k];
    }
    *(float4*)&pnew[base]   = make_float4(pn[0], pn[1], pn[2], pn[3]);
    *(float4*)&pnew[base+4] = make_float4(pn[4], pn[5], pn[6], pn[7]);
    if (storeQ) {   // r_new unused after the last iteration
      *(float4*)&rnew[base]   = make_float4(rn[0], rn[1], rn[2], rn[3]);
      *(float4*)&rnew[base+4] = make_float4(rn[4], rn[5], rn[6], rn[7]);
    }
    *(float4*)&xk[base]     = make_float4(xv[0], xv[1], xv[2], xv[3]);
    *(float4*)&xk[base+4]   = make_float4(xv[4], xv[5], xv[6], xv[7]);
  }
  __syncthreads();

  float accv[8];
  apply_M2(ssrc, bandv, Gs, tab, tid, oy0, ox0, accv);

  float s_den = 0.f, s_rq = 0.f, s_qq = 0.f;
  #pragma unroll
  for (int k = 0; k < 8; k++) {
    float qv = accv[k];
    s_den += pn[k]*qv;
    s_rq  += rn[k]*qv;
    s_qq  += qv*qv;
  }
  if (storeQ) {
    *(float4*)&qnew[base]   = make_float4(accv[0], accv[1], accv[2], accv[3]);
    *(float4*)&qnew[base+4] = make_float4(accv[4], accv[5], accv[6], accv[7]);
  }
  reduce3_atomic(s_den, s_rq, s_qq, red, &scal[it*8+bimg], &scal[48+it*8+bimg],
                 &scal[96+it*8+bimg]);
}

__launch_bounds__(256)
__global__ void k_final(const float* __restrict__ xk, const float* __restrict__ p,
                        const float* __restrict__ num, const float* __restrict__ den,
                        float* __restrict__ out) {
  const int tid = threadIdx.x;
  const int bimg = blockIdx.x >> 8;
  const size_t idx4 = (size_t)blockIdx.x * 256 + tid;
  const float al = num[bimg] / den[bimg];
  float4 xv = ((const float4*)xk)[idx4];
  float4 pv = ((const float4*)p)[idx4];
  float4 o;
  o.x = xv.x + al*pv.x; o.y = xv.y + al*pv.y; o.z = xv.z + al*pv.z; o.w = xv.w + al*pv.w;
  ((float4*)out)[idx4] = o;
}

extern "C" void kernel_launch(void* const* d_in, const int* in_sizes, int n_in,
                              void* d_out, int out_size, void* d_ws, size_t ws_size,
                              hipStream_t stream) {
  const float* sino = (const float*)d_in[0];
  const float* x    = (const float*)d_in[1];
  const float* laam = (const float*)d_in[2];
  const float* miu  = (const float*)d_in[3];
  const float* Kw   = (const float*)d_in[4];
  const float* Ka   = (const float*)d_in[5];
  const float* W1   = (const float*)d_in[6];
  const float* b1   = (const float*)d_in[7];
  const float* W2   = (const float*)d_in[8];
  const float* b2   = (const float*)d_in[9];
  const float* W3   = (const float*)d_in[10];
  const float* b3   = (const float*)d_in[11];

  float* ws = (float*)d_ws;
  float* tail = ws + (size_t)6*NTOT;
  float* tab  = tail;                  // 2025 (pad 2048)
  float* scal = tail + 2048;           // 192: den[48] rq[48] qq[48] rtr[48]
  ushort* w2pk = (ushort*)(scal + 192);
  uint*   w1pk = (uint*)(w2pk + 9216);
  uint*   b1pk = w1pk + 144;
  ushort* w3fr = (ushort*)(b1pk + 16);
  float* dout = (float*)d_out;

  k_prep<<<1, 1024, 0, stream>>>(Ka, Kw, miu, W1, b1, W2, W3, tab, w2pk, w1pk,
                                 b1pk, w3fr, scal);

  float* xk = ws;
  k_cnn<<<dim3(32,32,8), 512, 0, stream>>>(x, w2pk, w1pk, b1pk, w3fr, b2, b3, xk);

  dim3 mg(8,16,8);
  float* rA = ws + (size_t)NTOT;
  float* rB = ws + 2*(size_t)NTOT;
  float* pA = ws + 3*(size_t)NTOT;
  float* pB = ws + 4*(size_t)NTOT;
  float* qB = ws + 5*(size_t)NTOT;
  float* qA = dout;
  k_M0<<<mg,256,0,stream>>>(xk, sino, x, rA, pA, tab, Ka, Kw, laam, miu, &scal[144]);
  k_M<1><<<mg,256,0,stream>>>(pA, nullptr, qA, nullptr, tab,
                              nullptr, nullptr, &scal[0], &scal[48], &scal[96]);
  float *rc=rA, *rn=rB, *pc=pA, *pn=pB, *qc=qA, *qn=qB;
  for (int it = 1; it <= 5; it++) {
    k_it<<<mg,256,0,stream>>>(xk, rc, rn, pc, pn, qc, qn, tab, scal,
                              it, it < 5 ? 1 : 0);
    float* t;
    t = rc; rc = rn; rn = t;
    t = pc; pc = pn; pn = t;
    t = qc; qc = qn; qn = t;
  }
  k_final<<<2048,256,0,stream>>>(xk, pc, &scal[144+40], &scal[40], dout);
}